// Round 1
// baseline (7502.795 us; speedup 1.0000x reference)
//
#include <hip/hip_runtime.h>
#include <hip/hip_bf16.h>

#define B_SZ 16384
#define T_SZ 20
#define ZD 32

typedef __attribute__((ext_vector_type(8))) __bf16 bf16x8;
typedef __attribute__((ext_vector_type(4))) float f32x4;

__device__ __forceinline__ float sigm(float x) { return 1.f / (1.f + __expf(-x)); }
__device__ __forceinline__ float tanh_(float x) { return 1.f - 2.f / (__expf(2.f * x) + 1.f); }

// ---------------- weight prep: fp32 [W;U] -> bf16 MFMA B-fragment packing ----------------
// packed elem index = ((kt*64 + nt)*64 + lane)*8 + jj
// k = kt*32 + (lane>>4)*8 + jj ; n = nt*16 + (lane&15)
// matrices (KT count): m0 z2-L1 (11), m1 z2-L2 (16), m2 z1-L1 (12), m3 z1-L2 (16)
__global__ void prep_w(const float* __restrict__ W0, const float* __restrict__ U0,
                       const float* __restrict__ W1, const float* __restrict__ U1,
                       const float* __restrict__ W2, const float* __restrict__ U2,
                       const float* __restrict__ W3, const float* __restrict__ U3,
                       __bf16* __restrict__ wp)
{
    int idx = blockIdx.x * 256 + threadIdx.x;
    if (idx >= 1802240) return;
    const float *W, *U;
    int Fv, Kx, local;
    if (idx < 360448)       { W = W0; U = U0; Fv = 80;  Kx = 96;  local = idx; }
    else if (idx < 884736)  { W = W1; U = U1; Fv = 256; Kx = 256; local = idx - 360448; }
    else if (idx < 1277952) { W = W2; U = U2; Fv = 112; Kx = 128; local = idx - 884736; }
    else                    { W = W3; U = U3; Fv = 256; Kx = 256; local = idx - 1277952; }
    int jj = local & 7, lane = (local >> 3) & 63, nt = (local >> 9) & 63, kt = local >> 15;
    int k = kt * 32 + ((lane >> 4) << 3) + jj;
    int n = (nt << 4) + (lane & 15);
    float v = (k < Fv) ? W[k * 1024 + n] : (k < Kx ? 0.f : U[(k - Kx) * 1024 + n]);
    wp[idx] = (__bf16)v;
}

// ---------------- fragment helpers ----------------
__device__ __forceinline__ bf16x8 hfrag(const __bf16* hb, int row, int k)
{
    unsigned byte = (unsigned)row * 512u + (unsigned)k * 2u;
    byte ^= (unsigned)(row & 7) << 4;  // bank-conflict swizzle (G4)
    return *reinterpret_cast<const bf16x8*>(reinterpret_cast<const char*>(hb) + byte);
}
__device__ __forceinline__ void hwrite(__bf16* hb, int row, int col, float v)
{
    unsigned byte = (unsigned)row * 512u + (unsigned)col * 2u;
    byte ^= (unsigned)(row & 7) << 4;
    *reinterpret_cast<__bf16*>(reinterpret_cast<char*>(hb) + byte) = (__bf16)v;
}
__device__ __forceinline__ bf16x8 wfrag(const __bf16* wp, int kt, int nt, int lane)
{
    return *reinterpret_cast<const bf16x8*>(wp + ((((kt * 64) + nt) * 64 + lane) << 3));
}

template <int HASZ>
__device__ __forceinline__ bf16x8 xfrag(const float* __restrict__ x, const float* __restrict__ z2s,
                                        int row_b, int t, int k)
{
    float4 u0, u1;
    if (k < 80) {
        const float4* p = reinterpret_cast<const float4*>(x + ((size_t)row_b * T_SZ + t) * 80 + k);
        u0 = p[0]; u1 = p[1];
    } else if (HASZ && k < 112) {
        const float4* p = reinterpret_cast<const float4*>(z2s + (size_t)row_b * 32 + (k - 80));
        u0 = p[0]; u1 = p[1];
    } else {
        u0 = make_float4(0.f, 0.f, 0.f, 0.f); u1 = u0;
    }
    bf16x8 r;
    r[0] = (__bf16)u0.x; r[1] = (__bf16)u0.y; r[2] = (__bf16)u0.z; r[3] = (__bf16)u0.w;
    r[4] = (__bf16)u1.x; r[5] = (__bf16)u1.y; r[6] = (__bf16)u1.z; r[7] = (__bf16)u1.w;
    return r;
}

// ---------------- persistent stacked-LSTM branch kernel ----------------
// grid = 256 wgs x 512 thr (8 waves). Each wg: 64 batch rows, all T steps.
// wave w owns H-columns [w*32, w*32+32) for all 4 gates; c-state in regs (MFMA C/D layout:
// col = lane&15, row = (lane>>4)*4 + reg  [verified m89]).
template <int KTX, int HASZ>
__global__ void __launch_bounds__(512, 2)
lstm_branch(const float* __restrict__ x, const float* __restrict__ z2s,
            const __bf16* __restrict__ wp1, const __bf16* __restrict__ wp2,
            const float* __restrict__ b1g, const float* __restrict__ b2g,
            float* __restrict__ zpre)
{
    constexpr int KT1 = KTX + 8;
    __shared__ __align__(16) __bf16 h1b[64 * 256];
    __shared__ __align__(16) __bf16 h2b[64 * 256];

    const int tid = threadIdx.x;
    const int wid = tid >> 6;
    const int lane = tid & 63;
    const int r16 = lane & 15;
    const int kq = lane >> 4;
    const int b0 = blockIdx.x * 64;
    const int jw = wid * 32;

    for (int i = tid; i < 64 * 256 / 2; i += 512) {
        reinterpret_cast<unsigned*>(h1b)[i] = 0u;
        reinterpret_cast<unsigned*>(h2b)[i] = 0u;
    }

    float bias1[4][2], bias2[4][2];
#pragma unroll
    for (int g = 0; g < 4; ++g)
#pragma unroll
        for (int nl = 0; nl < 2; ++nl) {
            int col = g * 256 + jw + nl * 16 + r16;
            bias1[g][nl] = b1g[col];
            bias2[g][nl] = b2g[col];
        }

    f32x4 c1[2][4], c2[2][4];
#pragma unroll
    for (int nl = 0; nl < 2; ++nl)
#pragma unroll
        for (int m = 0; m < 4; ++m) {
            c1[nl][m] = f32x4{0.f, 0.f, 0.f, 0.f};
            c2[nl][m] = f32x4{0.f, 0.f, 0.f, 0.f};
        }

    __syncthreads();

    for (int t = 0; t < T_SZ; ++t) {
        // ---------- layer 1: z = [x_t | h1_old] @ [W1;U1] ----------
        float h1v[2][16];
#pragma unroll
        for (int nl = 0; nl < 2; ++nl) {
            f32x4 acc[4][4];
#pragma unroll
            for (int g = 0; g < 4; ++g)
#pragma unroll
                for (int m = 0; m < 4; ++m) acc[g][m] = f32x4{0.f, 0.f, 0.f, 0.f};
#pragma unroll
            for (int kt = 0; kt < KT1; ++kt) {
                bf16x8 a[4];
                if (kt < KTX) {
                    const int k = kt * 32 + kq * 8;
#pragma unroll
                    for (int m = 0; m < 4; ++m) a[m] = xfrag<HASZ>(x, z2s, b0 + m * 16 + r16, t, k);
                } else {
                    const int kb = (kt - KTX) * 32 + kq * 8;
#pragma unroll
                    for (int m = 0; m < 4; ++m) a[m] = hfrag(h1b, m * 16 + r16, kb);
                }
#pragma unroll
                for (int g = 0; g < 4; ++g) {
                    bf16x8 bw = wfrag(wp1, kt, g * 16 + wid * 2 + nl, lane);
#pragma unroll
                    for (int m = 0; m < 4; ++m)
                        acc[g][m] = __builtin_amdgcn_mfma_f32_16x16x32_bf16(a[m], bw, acc[g][m], 0, 0, 0);
                }
            }
#pragma unroll
            for (int m = 0; m < 4; ++m)
#pragma unroll
                for (int q = 0; q < 4; ++q) {
                    float cn = sigm(acc[1][m][q] + bias1[1][nl]) * c1[nl][m][q]
                             + sigm(acc[0][m][q] + bias1[0][nl]) * tanh_(acc[2][m][q] + bias1[2][nl]);
                    c1[nl][m][q] = cn;
                    h1v[nl][m * 4 + q] = sigm(acc[3][m][q] + bias1[3][nl]) * tanh_(cn);
                }
        }
        __syncthreads();  // all waves done reading h1_old
#pragma unroll
        for (int nl = 0; nl < 2; ++nl)
#pragma unroll
            for (int m = 0; m < 4; ++m)
#pragma unroll
                for (int q = 0; q < 4; ++q)
                    hwrite(h1b, m * 16 + kq * 4 + q, jw + nl * 16 + r16, h1v[nl][m * 4 + q]);
        __syncthreads();  // h1_new visible

        // ---------- layer 2: z = [h1_new | h2_old] @ [W2;U2] ----------
        float h2v[2][16];
#pragma unroll
        for (int nl = 0; nl < 2; ++nl) {
            f32x4 acc[4][4];
#pragma unroll
            for (int g = 0; g < 4; ++g)
#pragma unroll
                for (int m = 0; m < 4; ++m) acc[g][m] = f32x4{0.f, 0.f, 0.f, 0.f};
#pragma unroll
            for (int kt = 0; kt < 16; ++kt) {
                const int kb = (kt & 7) * 32 + kq * 8;
                bf16x8 a[4];
#pragma unroll
                for (int m = 0; m < 4; ++m) a[m] = hfrag(kt < 8 ? h1b : h2b, m * 16 + r16, kb);
#pragma unroll
                for (int g = 0; g < 4; ++g) {
                    bf16x8 bw = wfrag(wp2, kt, g * 16 + wid * 2 + nl, lane);
#pragma unroll
                    for (int m = 0; m < 4; ++m)
                        acc[g][m] = __builtin_amdgcn_mfma_f32_16x16x32_bf16(a[m], bw, acc[g][m], 0, 0, 0);
                }
            }
#pragma unroll
            for (int m = 0; m < 4; ++m)
#pragma unroll
                for (int q = 0; q < 4; ++q) {
                    float cn = sigm(acc[1][m][q] + bias2[1][nl]) * c2[nl][m][q]
                             + sigm(acc[0][m][q] + bias2[0][nl]) * tanh_(acc[2][m][q] + bias2[2][nl]);
                    c2[nl][m][q] = cn;
                    h2v[nl][m * 4 + q] = sigm(acc[3][m][q] + bias2[3][nl]) * tanh_(cn);
                }
        }
        __syncthreads();  // all waves done reading h2_old
#pragma unroll
        for (int nl = 0; nl < 2; ++nl)
#pragma unroll
            for (int m = 0; m < 4; ++m)
#pragma unroll
                for (int q = 0; q < 4; ++q)
                    hwrite(h2b, m * 16 + kq * 4 + q, jw + nl * 16 + r16, h2v[nl][m * 4 + q]);
        __syncthreads();
    }

    // final cell states -> zpre (B x 512): [c1 | c2]
#pragma unroll
    for (int nl = 0; nl < 2; ++nl)
#pragma unroll
        for (int m = 0; m < 4; ++m)
#pragma unroll
            for (int q = 0; q < 4; ++q) {
                int row = b0 + m * 16 + kq * 4 + q;
                int col = jw + nl * 16 + r16;
                zpre[(size_t)row * 512 + col] = c1[nl][m][q];
                zpre[(size_t)row * 512 + 256 + col] = c2[nl][m][q];
            }
}

// ---------------- heads: mu/logvar GEMV (fp32 exact) + reparameterize ----------------
__global__ void head_k(const float* __restrict__ zpre,
                       const float* __restrict__ muW, const float* __restrict__ mub,
                       const float* __restrict__ lvW, const float* __restrict__ lvb,
                       const float* __restrict__ eps,
                       float* __restrict__ omu, float* __restrict__ olv, float* __restrict__ osm)
{
    int idx = blockIdx.x * 256 + threadIdx.x;
    int b = idx >> 5, j = idx & 31;
    const float* zr = zpre + (size_t)b * 512;
    float mu = mub[j], lv = lvb[j];
#pragma unroll 8
    for (int k = 0; k < 512; ++k) {
        float zv = zr[k];
        mu = fmaf(zv, muW[k * 32 + j], mu);
        lv = fmaf(zv, lvW[k * 32 + j], lv);
    }
    omu[idx] = mu;
    olv[idx] = lv;
    osm[idx] = fmaf(eps[idx], expf(0.5f * lv), mu);
}

extern "C" void kernel_launch(void* const* d_in, const int* in_sizes, int n_in,
                              void* d_out, int out_size, void* d_ws, size_t ws_size,
                              hipStream_t stream)
{
    const float* x    = (const float*)d_in[0];
    const float* eps1 = (const float*)d_in[1];
    const float* eps2 = (const float*)d_in[2];
    const float* z2W1 = (const float*)d_in[3];
    const float* z2U1 = (const float*)d_in[4];
    const float* z2b1 = (const float*)d_in[5];
    const float* z2W2 = (const float*)d_in[6];
    const float* z2U2 = (const float*)d_in[7];
    const float* z2b2 = (const float*)d_in[8];
    const float* z1W1 = (const float*)d_in[9];
    const float* z1U1 = (const float*)d_in[10];
    const float* z1b1 = (const float*)d_in[11];
    const float* z1W2 = (const float*)d_in[12];
    const float* z1U2 = (const float*)d_in[13];
    const float* z1b2 = (const float*)d_in[14];
    const float* mu2W = (const float*)d_in[15];
    const float* mu2b = (const float*)d_in[16];
    const float* lv2W = (const float*)d_in[17];
    const float* lv2b = (const float*)d_in[18];
    const float* mu1W = (const float*)d_in[19];
    const float* mu1b = (const float*)d_in[20];
    const float* lv1W = (const float*)d_in[21];
    const float* lv1b = (const float*)d_in[22];

    __bf16* wp  = (__bf16*)d_ws;                        // 1,802,240 bf16 = 3.6 MB
    float* zpre = (float*)((char*)d_ws + (4u << 20));   // B x 512 fp32 = 33.5 MB (reused by both branches)

    float* out = (float*)d_out;
    const int BZ = B_SZ * ZD;
    float* z1mu = out;           float* z1lv = out + BZ;     float* z1sm = out + 2 * BZ;
    float* z2mu = out + 3 * BZ;  float* z2lv = out + 4 * BZ; float* z2sm = out + 5 * BZ;

    prep_w<<<7040, 256, 0, stream>>>(z2W1, z2U1, z2W2, z2U2, z1W1, z1U1, z1W2, z1U2, wp);

    // z2 branch (input = x, F=80 -> KTX=3)
    lstm_branch<3, 0><<<256, 512, 0, stream>>>(x, nullptr, wp, wp + 360448, z2b1, z2b2, zpre);
    head_k<<<BZ / 256, 256, 0, stream>>>(zpre, mu2W, mu2b, lv2W, lv2b, eps2, z2mu, z2lv, z2sm);

    // z1 branch (input = [x | z2_sample], F=112 -> KTX=4); reads z2sm written above
    lstm_branch<4, 1><<<256, 512, 0, stream>>>(x, z2sm, wp + 884736, wp + 1277952, z1b1, z1b2, zpre);
    head_k<<<BZ / 256, 256, 0, stream>>>(zpre, mu1W, mu1b, lv1W, lv1b, eps1, z1mu, z1lv, z1sm);
}

// Round 2
// 4050.028 us; speedup vs baseline: 1.8525x; 1.8525x over previous
//
#include <hip/hip_runtime.h>
#include <hip/hip_bf16.h>

#define B_SZ 16384
#define T_SZ 20
#define ZD 32

typedef __attribute__((ext_vector_type(8))) __bf16 bf16x8;
typedef __attribute__((ext_vector_type(4))) float f32x4;

__device__ __forceinline__ float sigm(float x) { return 1.f / (1.f + __expf(-x)); }
__device__ __forceinline__ float tanh_(float x) { return 1.f - 2.f / (__expf(2.f * x) + 1.f); }

// ---------------- weight prep: fp32 [W;U] -> bf16 MFMA B-fragment packing ----------------
// packed elem idx = ((kt*64 + NT)*64 + lane)*8 + jj
// k = kt*32 + (lane>>4)*8 + jj
// NT -> orig col: gate=(NT&7)>>1, hh=NT&1, wgn=NT>>3 ; n = gate*256 + wgn*32 + hh*16 + (lane&15)
// value = k<Fx ? W[k][n] : (k<Kx ? 0 : U[k-Kx][n])
// matrices: m0 z2-L1 (KT=12,Fx=80,Kx=128)  m1 z2-L2 (16,256,256)
//           m2 z1-L1 (12,112,128)          m3 z1-L2 (16,256,256)
__global__ void prep_w(const float* __restrict__ W0, const float* __restrict__ U0,
                       const float* __restrict__ W1, const float* __restrict__ U1,
                       const float* __restrict__ W2, const float* __restrict__ U2,
                       const float* __restrict__ W3, const float* __restrict__ U3,
                       __bf16* __restrict__ wp)
{
    int idx = blockIdx.x * 256 + threadIdx.x;
    if (idx >= 1835008) return;
    const float *W, *U;
    int Fx, Kx, local;
    if (idx < 393216)       { W = W0; U = U0; Fx = 80;  Kx = 128; local = idx; }
    else if (idx < 917504)  { W = W1; U = U1; Fx = 256; Kx = 256; local = idx - 393216; }
    else if (idx < 1310720) { W = W2; U = U2; Fx = 112; Kx = 128; local = idx - 917504; }
    else                    { W = W3; U = U3; Fx = 256; Kx = 256; local = idx - 1310720; }
    int jj = local & 7, lane = (local >> 3) & 63, NT = (local >> 9) & 63, kt = local >> 15;
    int k = kt * 32 + ((lane >> 4) << 3) + jj;
    int gate = (NT & 7) >> 1, hh = NT & 1, wgn = NT >> 3;
    int n = gate * 256 + wgn * 32 + hh * 16 + (lane & 15);
    float v = (k < Fx) ? W[k * 1024 + n] : (k < Kx ? 0.f : U[(k - Kx) * 1024 + n]);
    wp[idx] = (__bf16)v;
}

// ---------------- A-fragment gather from fp32 x (+ optional z2 sample) ----------------
template <int HASZ>
__device__ __forceinline__ bf16x8 xfrag(const float* __restrict__ x, const float* __restrict__ z2s,
                                        int row_b, int t, int k)
{
    float4 u0, u1;
    if (k < 80) {
        const float4* p = reinterpret_cast<const float4*>(x + ((size_t)row_b * T_SZ + t) * 80 + k);
        u0 = p[0]; u1 = p[1];
    } else if (HASZ && k < 112) {
        const float4* p = reinterpret_cast<const float4*>(z2s + (size_t)row_b * 32 + (k - 80));
        u0 = p[0]; u1 = p[1];
    } else {
        u0 = make_float4(0.f, 0.f, 0.f, 0.f); u1 = u0;
    }
    bf16x8 r;
    r[0] = (__bf16)u0.x; r[1] = (__bf16)u0.y; r[2] = (__bf16)u0.z; r[3] = (__bf16)u0.w;
    r[4] = (__bf16)u1.x; r[5] = (__bf16)u1.y; r[6] = (__bf16)u1.z; r[7] = (__bf16)u1.w;
    return r;
}

// ---------------- fused per-step LSTM-layer GEMM ----------------
// MODE 0: layer1 of z2 (A = [x_t | pad | h1_prev], KT=12)
// MODE 1: layer1 of z1 (A = [x_t | z2s | pad | h1_prev], KT=12)
// MODE 2: layer2       (A = [h1_cur | h2_prev], KT=16)
// grid = 1024 (bid = wgn*128 + mid  => all 8 n-slices of an M-band on one XCD)
// block = 256 (4 waves); wave w owns rows [mid*128 + w*32, +32), all 128 wg cols.
// wg cols = 32 h-cols of [gate-interleaved] packed B; nt = gate*2 + hh.
// Epilogue: lane-local i,f,g,o per h-col -> c update (fp32 global) + h write (bf16).
template <int MODE>
__global__ void __launch_bounds__(256, 4)
step_gemm(const float* __restrict__ x, const float* __restrict__ z2s, int t,
          const __bf16* __restrict__ hA, const __bf16* __restrict__ hB,
          const __bf16* __restrict__ wp, const float* __restrict__ bias,
          float* __restrict__ cbuf, __bf16* __restrict__ hout)
{
    constexpr int KT = (MODE == 2) ? 16 : 12;
    const int tid = threadIdx.x;
    const int w = tid >> 6, lane = tid & 63;
    const int r16 = lane & 15, kq = lane >> 4;
    const int bid = blockIdx.x;
    const int mid = bid & 127, wgn = bid >> 7;
    const int rb = mid * 128 + w * 32;

    f32x4 acc[8][2];
#pragma unroll
    for (int nt = 0; nt < 8; ++nt)
#pragma unroll
        for (int m = 0; m < 2; ++m) acc[nt][m] = f32x4{0.f, 0.f, 0.f, 0.f};

#pragma unroll
    for (int kt = 0; kt < KT; ++kt) {
        bf16x8 a[2];
        if (MODE < 2 && kt < 4) {
            const int k = kt * 32 + kq * 8;
            a[0] = xfrag<MODE == 1>(x, z2s, rb + r16, t, k);
            a[1] = xfrag<MODE == 1>(x, z2s, rb + 16 + r16, t, k);
        } else {
            const __bf16* hs;
            int hk;
            if (MODE < 2)      { hs = hA; hk = kt * 32 - 128 + kq * 8; }
            else if (kt < 8)   { hs = hA; hk = kt * 32 + kq * 8; }
            else               { hs = hB; hk = kt * 32 - 256 + kq * 8; }
            a[0] = *reinterpret_cast<const bf16x8*>(hs + (size_t)(rb + r16) * 256 + hk);
            a[1] = *reinterpret_cast<const bf16x8*>(hs + (size_t)(rb + 16 + r16) * 256 + hk);
        }
        const __bf16* wk = wp + (((size_t)(kt * 64 + wgn * 8) * 64 + lane) << 3);
#pragma unroll
        for (int nt = 0; nt < 8; ++nt) {
            bf16x8 b = *reinterpret_cast<const bf16x8*>(wk + nt * 512);
            acc[nt][0] = __builtin_amdgcn_mfma_f32_16x16x32_bf16(a[0], b, acc[nt][0], 0, 0, 0);
            acc[nt][1] = __builtin_amdgcn_mfma_f32_16x16x32_bf16(a[1], b, acc[nt][1], 0, 0, 0);
        }
    }

    // ---- fused LSTM cell epilogue ----
    float bg[2][4];
#pragma unroll
    for (int hh = 0; hh < 2; ++hh)
#pragma unroll
        for (int gate = 0; gate < 4; ++gate)
            bg[hh][gate] = bias[gate * 256 + wgn * 32 + hh * 16 + r16];

#pragma unroll
    for (int m = 0; m < 2; ++m)
#pragma unroll
        for (int hh = 0; hh < 2; ++hh) {
            const int hcol = wgn * 32 + hh * 16 + r16;
            f32x4 zi = acc[0 + hh][m], zf = acc[2 + hh][m], zg = acc[4 + hh][m], zo = acc[6 + hh][m];
#pragma unroll
            for (int q = 0; q < 4; ++q) {
                int row = rb + m * 16 + kq * 4 + q;
                size_t off = (size_t)row * 256 + hcol;
                float co = cbuf[off];
                float cn = sigm(zf[q] + bg[hh][1]) * co
                         + sigm(zi[q] + bg[hh][0]) * tanh_(zg[q] + bg[hh][2]);
                cbuf[off] = cn;
                hout[off] = (__bf16)(sigm(zo[q] + bg[hh][3]) * tanh_(cn));
            }
        }
}

// ---------------- heads: mu/logvar GEMV (fp32 exact) + reparameterize ----------------
__global__ void head_k(const float* __restrict__ c1, const float* __restrict__ c2,
                       const float* __restrict__ muW, const float* __restrict__ mub,
                       const float* __restrict__ lvW, const float* __restrict__ lvb,
                       const float* __restrict__ eps,
                       float* __restrict__ omu, float* __restrict__ olv, float* __restrict__ osm)
{
    int idx = blockIdx.x * 256 + threadIdx.x;
    int b = idx >> 5, j = idx & 31;
    const float* r1 = c1 + (size_t)b * 256;
    const float* r2 = c2 + (size_t)b * 256;
    float mu = mub[j], lv = lvb[j];
#pragma unroll 8
    for (int k = 0; k < 256; ++k) {
        float zv = r1[k];
        mu = fmaf(zv, muW[k * 32 + j], mu);
        lv = fmaf(zv, lvW[k * 32 + j], lv);
    }
#pragma unroll 8
    for (int k = 0; k < 256; ++k) {
        float zv = r2[k];
        mu = fmaf(zv, muW[(k + 256) * 32 + j], mu);
        lv = fmaf(zv, lvW[(k + 256) * 32 + j], lv);
    }
    omu[idx] = mu;
    olv[idx] = lv;
    osm[idx] = fmaf(eps[idx], expf(0.5f * lv), mu);
}

extern "C" void kernel_launch(void* const* d_in, const int* in_sizes, int n_in,
                              void* d_out, int out_size, void* d_ws, size_t ws_size,
                              hipStream_t stream)
{
    const float* x    = (const float*)d_in[0];
    const float* eps1 = (const float*)d_in[1];
    const float* eps2 = (const float*)d_in[2];
    const float* z2W1 = (const float*)d_in[3];
    const float* z2U1 = (const float*)d_in[4];
    const float* z2b1 = (const float*)d_in[5];
    const float* z2W2 = (const float*)d_in[6];
    const float* z2U2 = (const float*)d_in[7];
    const float* z2b2 = (const float*)d_in[8];
    const float* z1W1 = (const float*)d_in[9];
    const float* z1U1 = (const float*)d_in[10];
    const float* z1b1 = (const float*)d_in[11];
    const float* z1W2 = (const float*)d_in[12];
    const float* z1U2 = (const float*)d_in[13];
    const float* z1b2 = (const float*)d_in[14];
    const float* mu2W = (const float*)d_in[15];
    const float* mu2b = (const float*)d_in[16];
    const float* lv2W = (const float*)d_in[17];
    const float* lv2b = (const float*)d_in[18];
    const float* mu1W = (const float*)d_in[19];
    const float* mu1b = (const float*)d_in[20];
    const float* lv1W = (const float*)d_in[21];
    const float* lv1b = (const float*)d_in[22];

    char* ws = (char*)d_ws;
    __bf16* wp   = (__bf16*)ws;                        // 1,835,008 bf16 = 3.67 MB
    __bf16* h1a  = (__bf16*)(ws + 4194304);            // B x 256 bf16 = 8 MB
    __bf16* h2a  = (__bf16*)(ws + 12582912);
    __bf16* h1b  = (__bf16*)(ws + 20971520);
    __bf16* h2b  = (__bf16*)(ws + 29360128);
    float*  c1   = (float*)(ws + 37748736);            // B x 256 fp32 = 16 MB
    float*  c2   = (float*)(ws + 54525952);            // end = 71,303,168

    __bf16* h1[2] = {h1a, h1b};
    __bf16* h2[2] = {h2a, h2b};

    float* out = (float*)d_out;
    const int BZ = B_SZ * ZD;
    float* z1mu = out;           float* z1lv = out + BZ;     float* z1sm = out + 2 * BZ;
    float* z2mu = out + 3 * BZ;  float* z2lv = out + 4 * BZ; float* z2sm = out + 5 * BZ;

    prep_w<<<7168, 256, 0, stream>>>(z2W1, z2U1, z2W2, z2U2, z1W1, z1U1, z1W2, z1U2, wp);

    const __bf16* wpL1z2 = wp;
    const __bf16* wpL2z2 = wp + 393216;
    const __bf16* wpL1z1 = wp + 917504;
    const __bf16* wpL2z1 = wp + 1310720;

    // ---- z2 branch ----
    hipMemsetAsync(ws + 20971520, 0, 50331648, stream);  // h1b, h2b, c1, c2 = 0
    for (int t = 0; t < T_SZ; ++t) {
        int cur = t & 1, prv = cur ^ 1;
        step_gemm<0><<<1024, 256, 0, stream>>>(x, nullptr, t, h1[prv], nullptr,
                                               wpL1z2, z2b1, c1, h1[cur]);
        step_gemm<2><<<1024, 256, 0, stream>>>(nullptr, nullptr, t, h1[cur], h2[prv],
                                               wpL2z2, z2b2, c2, h2[cur]);
    }
    head_k<<<BZ / 256, 256, 0, stream>>>(c1, c2, mu2W, mu2b, lv2W, lv2b, eps2, z2mu, z2lv, z2sm);

    // ---- z1 branch (reads z2sm) ----
    hipMemsetAsync(ws + 20971520, 0, 50331648, stream);
    for (int t = 0; t < T_SZ; ++t) {
        int cur = t & 1, prv = cur ^ 1;
        step_gemm<1><<<1024, 256, 0, stream>>>(x, z2sm, t, h1[prv], nullptr,
                                               wpL1z1, z1b1, c1, h1[cur]);
        step_gemm<2><<<1024, 256, 0, stream>>>(nullptr, nullptr, t, h1[cur], h2[prv],
                                               wpL2z1, z1b2, c2, h2[cur]);
    }
    head_k<<<BZ / 256, 256, 0, stream>>>(c1, c2, mu1W, mu1b, lv1W, lv1b, eps1, z1mu, z1lv, z1sm);
}

// Round 4
// 2509.339 us; speedup vs baseline: 2.9899x; 1.6140x over previous
//
#include <hip/hip_runtime.h>
#include <hip/hip_bf16.h>

#define B_SZ 16384
#define T_SZ 20

typedef __attribute__((ext_vector_type(8))) __bf16 bf16x8;
typedef __attribute__((ext_vector_type(4))) float f32x4;

__device__ __forceinline__ float sigm(float x){ return 1.f/(1.f+__expf(-x)); }
__device__ __forceinline__ float tanh_(float x){ return 1.f-2.f/(__expf(2.f*x)+1.f); }

// packed weight element offsets (bf16 elements)
#define OFF_L1Z2 0
#define OFF_L2Z2 360448
#define OFF_L1Z1 884736
#define OFF_L2Z1 1277952
#define OFF_HZ2  1802240
#define OFF_HZ1  1835008   // = OFF_HZ2 + 16*4*512 (each head mat is exactly 32768 elems)
#define WP_TOT   1867776

// ---------------- weight prep ----------------
// LSTM mats: elem idx (within mat) = ((wgn*KT + kt)*8 + nt8)*512 + lane*8 + jj
//   gate=nt8>>1, hh=nt8&1; n = gate*256 + wgn*32 + hh*16 + (lane&15)
//   k = kt*32 + (lane>>4)*8 + jj;  v = k<Fx ? W[k][n] : (k<Kx ? 0 : U[k-Kx][n])
// head mats: idx = (kt*4 + nt)*512 + lane*8 + jj ; kt in 0..15 (K=512);
//   nt<2 -> muW col nt*16+(lane&15), else lvW col (nt-2)*16+(lane&15)
__global__ void prep_w(const float* __restrict__ W0, const float* __restrict__ U0,
                       const float* __restrict__ W1, const float* __restrict__ U1,
                       const float* __restrict__ W2, const float* __restrict__ U2,
                       const float* __restrict__ W3, const float* __restrict__ U3,
                       const float* __restrict__ muW2, const float* __restrict__ lvW2,
                       const float* __restrict__ muW1, const float* __restrict__ lvW1,
                       __bf16* __restrict__ wp)
{
    int idx = blockIdx.x * 256 + threadIdx.x;
    if (idx >= WP_TOT) return;
    if (idx < OFF_HZ2) {
        const float *W, *U;
        int Fx, Kx, KT, local;
        if (idx < OFF_L2Z2)      { W = W0; U = U0; Fx = 80;  Kx = 96;  KT = 11; local = idx; }
        else if (idx < OFF_L1Z1) { W = W1; U = U1; Fx = 256; Kx = 256; KT = 16; local = idx - OFF_L2Z2; }
        else if (idx < OFF_L2Z1) { W = W2; U = U2; Fx = 112; Kx = 128; KT = 12; local = idx - OFF_L1Z1; }
        else                     { W = W3; U = U3; Fx = 256; Kx = 256; KT = 16; local = idx - OFF_L2Z1; }
        int jj = local & 7, lane = (local >> 3) & 63, nt8 = (local >> 9) & 7, rest = local >> 12;
        int kt = rest % KT, wgn = rest / KT;
        int gate = nt8 >> 1, hh = nt8 & 1;
        int n = gate * 256 + wgn * 32 + hh * 16 + (lane & 15);
        int k = kt * 32 + ((lane >> 4) << 3) + jj;
        float v = (k < Fx) ? W[k * 1024 + n] : (k < Kx ? 0.f : U[(k - Kx) * 1024 + n]);
        wp[idx] = (__bf16)v;
    } else {
        int base = (idx < OFF_HZ1) ? OFF_HZ2 : OFF_HZ1;
        const float* mw = (idx < OFF_HZ1) ? muW2 : muW1;
        const float* lw = (idx < OFF_HZ1) ? lvW2 : lvW1;
        int local = idx - base;   // in [0, 32768)
        int jj = local & 7, lane = (local >> 3) & 63, nt = (local >> 9) & 3, kt = local >> 11; // kt 0..15
        int k = kt * 32 + ((lane >> 4) << 3) + jj;   // 0..511
        int c16 = lane & 15;
        float v = (nt < 2) ? mw[k * 32 + nt * 16 + c16] : lw[k * 32 + (nt - 2) * 16 + c16];
        wp[idx] = (__bf16)v;
    }
}

// ---------------- async 16B global -> LDS ----------------
__device__ __forceinline__ void stage16(const __bf16* g, __bf16* l)
{
    __builtin_amdgcn_global_load_lds(
        (const __attribute__((address_space(1))) unsigned*)g,
        (__attribute__((address_space(3))) unsigned*)l, 16, 0, 0);
}

// ---------------- A-fragment from fp32 x / bf16 z2 sample ----------------
template <int HASZ>
__device__ __forceinline__ bf16x8 xfrag(const float* __restrict__ x, const __bf16* __restrict__ z2b,
                                        int row, int t, int k)
{
    bf16x8 r;
    if (k < 80) {
        const float4* p = reinterpret_cast<const float4*>(x + ((size_t)row * T_SZ + t) * 80 + k);
        float4 u0 = p[0], u1 = p[1];
        r[0] = (__bf16)u0.x; r[1] = (__bf16)u0.y; r[2] = (__bf16)u0.z; r[3] = (__bf16)u0.w;
        r[4] = (__bf16)u1.x; r[5] = (__bf16)u1.y; r[6] = (__bf16)u1.z; r[7] = (__bf16)u1.w;
    } else if (HASZ && k < 112) {
        r = *reinterpret_cast<const bf16x8*>(z2b + (size_t)row * 32 + (k - 80));
    } else {
#pragma unroll
        for (int i = 0; i < 8; ++i) r[i] = (__bf16)0.f;
    }
    return r;
}

// ---------------- fused per-step LSTM-layer GEMM (LDS-staged B, 2-kt phases) ----------------
// MODE 0: z2 layer1 (KT=11, A=[x|pad|h1p])   MODE 1: z1 layer1 (KT=12, A=[x|z2|pad|h1p])
// MODE 2: layer2 (KT=16, A=[h1c|h2p])
// grid 512 (bid = wgn*64 + mid -> bid%8=mid%8 pins M-band to one XCD), block 512 = 8 waves.
// wave w: rows [mid*256 + w*32, +32), all 128 wg cols (= 32 h-cols x 4 gates, gate-interleaved).
template <int MODE>
__global__ void __launch_bounds__(512, 4)
step_gemm(const float* __restrict__ x, const __bf16* __restrict__ z2b, int t,
          const __bf16* __restrict__ hA, const __bf16* __restrict__ hB,
          const __bf16* __restrict__ wpm, const float* __restrict__ bias,
          float* __restrict__ cbuf, __bf16* __restrict__ hout)
{
    constexpr int KT  = (MODE == 0) ? 11 : (MODE == 1) ? 12 : 16;
    constexpr int XKT = (MODE == 0) ? 3  : (MODE == 1) ? 4  : 0;
    constexpr int P   = (KT + 1) / 2;
    __shared__ __align__(16) __bf16 Bs[4][4096];

    const int tid = threadIdx.x;
    const int w = tid >> 6, lane = tid & 63;
    const int r16 = lane & 15, kq = lane >> 4;
    const int mid = blockIdx.x & 63, wgn = blockIdx.x >> 6;
    const int rb = mid * 256 + w * 32;
    const __bf16* wpB = wpm + (size_t)wgn * KT * 4096;

    f32x4 acc[8][2];
#pragma unroll
    for (int nt = 0; nt < 8; ++nt)
#pragma unroll
        for (int m = 0; m < 2; ++m) acc[nt][m] = f32x4{0.f, 0.f, 0.f, 0.f};

    auto do_kt = [&](int kt) {
        bf16x8 a0, a1;
        if (MODE < 2 && kt < XKT) {
            int k = kt * 32 + kq * 8;
            a0 = xfrag<MODE == 1>(x, z2b, rb + r16, t, k);
            a1 = xfrag<MODE == 1>(x, z2b, rb + 16 + r16, t, k);
        } else {
            const __bf16* hs;
            int hk;
            if (MODE < 2)    { hs = hA; hk = (kt - XKT) * 32 + kq * 8; }
            else if (kt < 8) { hs = hA; hk = kt * 32 + kq * 8; }
            else             { hs = hB; hk = (kt - 8) * 32 + kq * 8; }
            hs += (size_t)(rb + r16) * 256 + hk;
            a0 = *reinterpret_cast<const bf16x8*>(hs);
            a1 = *reinterpret_cast<const bf16x8*>(hs + 16 * 256);
        }
        const __bf16* bp = &Bs[kt & 3][lane * 8];
#pragma unroll
        for (int nt = 0; nt < 8; ++nt) {
            bf16x8 bv = *reinterpret_cast<const bf16x8*>(bp + nt * 512);
            acc[nt][0] = __builtin_amdgcn_mfma_f32_16x16x32_bf16(a0, bv, acc[nt][0], 0, 0, 0);
            acc[nt][1] = __builtin_amdgcn_mfma_f32_16x16x32_bf16(a1, bv, acc[nt][1], 0, 0, 0);
        }
    };

    // prologue: stage kt 0,1
    stage16(wpB + tid * 8, &Bs[0][tid * 8]);
    stage16(wpB + 4096 + tid * 8, &Bs[1][tid * 8]);
    __syncthreads();

#pragma unroll
    for (int p = 0; p < P; ++p) {
        const int ks = 2 * p + 2;
        if (ks < KT)     stage16(wpB + (size_t)ks * 4096 + tid * 8, &Bs[ks & 3][tid * 8]);
        if (ks + 1 < KT) stage16(wpB + (size_t)(ks + 1) * 4096 + tid * 8, &Bs[(ks + 1) & 3][tid * 8]);
        do_kt(2 * p);
        if (2 * p + 1 < KT) do_kt(2 * p + 1);
        __syncthreads();
    }

    // ---- fused LSTM cell epilogue ----
    float bg[2][4];
#pragma unroll
    for (int hh = 0; hh < 2; ++hh)
#pragma unroll
        for (int gate = 0; gate < 4; ++gate)
            bg[hh][gate] = bias[gate * 256 + wgn * 32 + hh * 16 + r16];

#pragma unroll
    for (int m = 0; m < 2; ++m)
#pragma unroll
        for (int hh = 0; hh < 2; ++hh) {
            const int hcol = wgn * 32 + hh * 16 + r16;
            f32x4 zi = acc[0 + hh][m], zf = acc[2 + hh][m], zg = acc[4 + hh][m], zo = acc[6 + hh][m];
#pragma unroll
            for (int q = 0; q < 4; ++q) {
                int row = rb + m * 16 + kq * 4 + q;
                size_t off = (size_t)row * 256 + hcol;
                float co = cbuf[off];
                float cn = sigm(zf[q] + bg[hh][1]) * co
                         + sigm(zi[q] + bg[hh][0]) * tanh_(zg[q] + bg[hh][2]);
                cbuf[off] = cn;
                hout[off] = (__bf16)(sigm(zo[q] + bg[hh][3]) * tanh_(cn));
            }
        }
}

// ---------------- MFMA head: [c1|c2](16384x512) @ [muW|lvW](512x64) + reparam ----------------
// grid 256, block 128 (2 waves x 32 rows). nt 0,1 = mu cols, nt 2,3 = lv cols.
__global__ void __launch_bounds__(128, 4)
head_mfma(const float* __restrict__ c1, const float* __restrict__ c2,
          const __bf16* __restrict__ hp, const float* __restrict__ mub,
          const float* __restrict__ lvb, const float* __restrict__ eps,
          float* __restrict__ omu, float* __restrict__ olv, float* __restrict__ osm,
          __bf16* __restrict__ osb)
{
    const int tid = threadIdx.x;
    const int w = tid >> 6, lane = tid & 63;
    const int r16 = lane & 15, kq = lane >> 4;
    const int rb = blockIdx.x * 64 + w * 32;

    f32x4 acc[4][2];
#pragma unroll
    for (int nt = 0; nt < 4; ++nt)
#pragma unroll
        for (int m = 0; m < 2; ++m) acc[nt][m] = f32x4{0.f, 0.f, 0.f, 0.f};

#pragma unroll
    for (int kt = 0; kt < 16; ++kt) {
        const float* cs = (kt < 8) ? c1 : c2;
        int k = (kt & 7) * 32 + kq * 8;
        bf16x8 a[2];
#pragma unroll
        for (int m = 0; m < 2; ++m) {
            const float* pr = cs + (size_t)(rb + m * 16 + r16) * 256 + k;
            float4 u0 = reinterpret_cast<const float4*>(pr)[0];
            float4 u1 = reinterpret_cast<const float4*>(pr)[1];
            a[m][0] = (__bf16)u0.x; a[m][1] = (__bf16)u0.y; a[m][2] = (__bf16)u0.z; a[m][3] = (__bf16)u0.w;
            a[m][4] = (__bf16)u1.x; a[m][5] = (__bf16)u1.y; a[m][6] = (__bf16)u1.z; a[m][7] = (__bf16)u1.w;
        }
        const __bf16* hb = hp + kt * 2048 + lane * 8;
#pragma unroll
        for (int nt = 0; nt < 4; ++nt) {
            bf16x8 bv = *reinterpret_cast<const bf16x8*>(hb + nt * 512);
            acc[nt][0] = __builtin_amdgcn_mfma_f32_16x16x32_bf16(a[0], bv, acc[nt][0], 0, 0, 0);
            acc[nt][1] = __builtin_amdgcn_mfma_f32_16x16x32_bf16(a[1], bv, acc[nt][1], 0, 0, 0);
        }
    }

#pragma unroll
    for (int m = 0; m < 2; ++m)
#pragma unroll
        for (int q = 0; q < 4; ++q) {
            int row = rb + m * 16 + kq * 4 + q;
#pragma unroll
            for (int z = 0; z < 2; ++z) {
                int zc = z * 16 + r16;
                float mu = acc[z][m][q] + mub[zc];
                float lv = acc[z + 2][m][q] + lvb[zc];
                int idx = row * 32 + zc;
                omu[idx] = mu;
                olv[idx] = lv;
                float s = fmaf(eps[idx], expf(0.5f * lv), mu);
                osm[idx] = s;
                if (osb) osb[idx] = (__bf16)s;
            }
        }
}

extern "C" void kernel_launch(void* const* d_in, const int* in_sizes, int n_in,
                              void* d_out, int out_size, void* d_ws, size_t ws_size,
                              hipStream_t stream)
{
    const float* x    = (const float*)d_in[0];
    const float* eps1 = (const float*)d_in[1];
    const float* eps2 = (const float*)d_in[2];
    const float* z2W1 = (const float*)d_in[3];
    const float* z2U1 = (const float*)d_in[4];
    const float* z2b1 = (const float*)d_in[5];
    const float* z2W2 = (const float*)d_in[6];
    const float* z2U2 = (const float*)d_in[7];
    const float* z2b2 = (const float*)d_in[8];
    const float* z1W1 = (const float*)d_in[9];
    const float* z1U1 = (const float*)d_in[10];
    const float* z1b1 = (const float*)d_in[11];
    const float* z1W2 = (const float*)d_in[12];
    const float* z1U2 = (const float*)d_in[13];
    const float* z1b2 = (const float*)d_in[14];
    const float* mu2W = (const float*)d_in[15];
    const float* mu2b = (const float*)d_in[16];
    const float* lv2W = (const float*)d_in[17];
    const float* lv2b = (const float*)d_in[18];
    const float* mu1W = (const float*)d_in[19];
    const float* mu1b = (const float*)d_in[20];
    const float* lv1W = (const float*)d_in[21];
    const float* lv1b = (const float*)d_in[22];

    char* ws = (char*)d_ws;
    __bf16* wp   = (__bf16*)ws;                       // WP_TOT bf16 = 3.74 MB
    __bf16* z2sb = (__bf16*)(ws + 4194304);           // B x 32 bf16 = 1 MB
    __bf16* h1a  = (__bf16*)(ws + 5242880);           // B x 256 bf16 = 8 MB
    __bf16* h2a  = (__bf16*)(ws + 13631488);
    __bf16* h1b  = (__bf16*)(ws + 22020096);
    __bf16* h2b  = (__bf16*)(ws + 30408704);
    float*  c1   = (float*)(ws + 38797312);           // B x 256 fp32 = 16 MB
    float*  c2   = (float*)(ws + 55574528);           // end 72,351,744

    __bf16* h1[2] = {h1a, h1b};
    __bf16* h2[2] = {h2a, h2b};

    float* out = (float*)d_out;
    const int BZ = B_SZ * 32;
    float* z1mu = out;           float* z1lv = out + BZ;     float* z1sm = out + 2 * BZ;
    float* z2mu = out + 3 * BZ;  float* z2lv = out + 4 * BZ; float* z2sm = out + 5 * BZ;

    prep_w<<<7296, 256, 0, stream>>>(z2W1, z2U1, z2W2, z2U2, z1W1, z1U1, z1W2, z1U2,
                                     mu2W, lv2W, mu1W, lv1W, wp);

    // ---- z2 branch ----
    hipMemsetAsync(ws + 22020096, 0, 50331648, stream);  // h1b, h2b, c1, c2 = 0
    for (int t = 0; t < T_SZ; ++t) {
        int cur = t & 1, prv = cur ^ 1;
        step_gemm<0><<<512, 512, 0, stream>>>(x, nullptr, t, h1[prv], nullptr,
                                              wp + OFF_L1Z2, z2b1, c1, h1[cur]);
        step_gemm<2><<<512, 512, 0, stream>>>(nullptr, nullptr, t, h1[cur], h2[prv],
                                              wp + OFF_L2Z2, z2b2, c2, h2[cur]);
    }
    head_mfma<<<256, 128, 0, stream>>>(c1, c2, wp + OFF_HZ2, mu2b, lv2b, eps2,
                                       z2mu, z2lv, z2sm, z2sb);

    // ---- z1 branch ----
    hipMemsetAsync(ws + 22020096, 0, 50331648, stream);
    for (int t = 0; t < T_SZ; ++t) {
        int cur = t & 1, prv = cur ^ 1;
        step_gemm<1><<<512, 512, 0, stream>>>(x, z2sb, t, h1[prv], nullptr,
                                              wp + OFF_L1Z1, z1b1, c1, h1[cur]);
        step_gemm<2><<<512, 512, 0, stream>>>(nullptr, nullptr, t, h1[cur], h2[prv],
                                              wp + OFF_L2Z1, z1b2, c2, h2[cur]);
    }
    head_mfma<<<256, 128, 0, stream>>>(c1, c2, wp + OFF_HZ1, mu1b, lv1b, eps1,
                                       z1mu, z1lv, z1sm, nullptr);
}

// Round 5
// 2372.794 us; speedup vs baseline: 3.1620x; 1.0575x over previous
//
#include <hip/hip_runtime.h>
#include <hip/hip_bf16.h>

#define B_SZ 16384
#define T_SZ 20

typedef __attribute__((ext_vector_type(8))) __bf16 bf16x8;
typedef __attribute__((ext_vector_type(4))) float f32x4;

__device__ __forceinline__ float sigm(float x){ return 1.f/(1.f+__expf(-x)); }
__device__ __forceinline__ float tanh_(float x){ return 1.f-2.f/(__expf(2.f*x)+1.f); }

// packed weight element offsets (bf16 elements)
#define OFF_L1Z2 0
#define OFF_L2Z2 360448
#define OFF_L1Z1 884736
#define OFF_L2Z1 1277952
#define OFF_HZ2  1802240
#define OFF_HZ1  1835008
#define WP_TOT   1867776

// ---------------- weight prep (unchanged from round 4) ----------------
__global__ void prep_w(const float* __restrict__ W0, const float* __restrict__ U0,
                       const float* __restrict__ W1, const float* __restrict__ U1,
                       const float* __restrict__ W2, const float* __restrict__ U2,
                       const float* __restrict__ W3, const float* __restrict__ U3,
                       const float* __restrict__ muW2, const float* __restrict__ lvW2,
                       const float* __restrict__ muW1, const float* __restrict__ lvW1,
                       __bf16* __restrict__ wp)
{
    int idx = blockIdx.x * 256 + threadIdx.x;
    if (idx >= WP_TOT) return;
    if (idx < OFF_HZ2) {
        const float *W, *U;
        int Fx, Kx, KT, local;
        if (idx < OFF_L2Z2)      { W = W0; U = U0; Fx = 80;  Kx = 96;  KT = 11; local = idx; }
        else if (idx < OFF_L1Z1) { W = W1; U = U1; Fx = 256; Kx = 256; KT = 16; local = idx - OFF_L2Z2; }
        else if (idx < OFF_L2Z1) { W = W2; U = U2; Fx = 112; Kx = 128; KT = 12; local = idx - OFF_L1Z1; }
        else                     { W = W3; U = U3; Fx = 256; Kx = 256; KT = 16; local = idx - OFF_L2Z1; }
        int jj = local & 7, lane = (local >> 3) & 63, nt8 = (local >> 9) & 7, rest = local >> 12;
        int kt = rest % KT, wgn = rest / KT;
        int gate = nt8 >> 1, hh = nt8 & 1;
        int n = gate * 256 + wgn * 32 + hh * 16 + (lane & 15);
        int k = kt * 32 + ((lane >> 4) << 3) + jj;
        float v = (k < Fx) ? W[k * 1024 + n] : (k < Kx ? 0.f : U[(k - Kx) * 1024 + n]);
        wp[idx] = (__bf16)v;
    } else {
        int base = (idx < OFF_HZ1) ? OFF_HZ2 : OFF_HZ1;
        const float* mw = (idx < OFF_HZ1) ? muW2 : muW1;
        const float* lw = (idx < OFF_HZ1) ? lvW2 : lvW1;
        int local = idx - base;
        int jj = local & 7, lane = (local >> 3) & 63, nt = (local >> 9) & 3, kt = local >> 11;
        int k = kt * 32 + ((lane >> 4) << 3) + jj;
        int c16 = lane & 15;
        float v = (nt < 2) ? mw[k * 32 + nt * 16 + c16] : lw[k * 32 + (nt - 2) * 16 + c16];
        wp[idx] = (__bf16)v;
    }
}

// ---------------- x fp32 -> xb bf16 [B][T][128] (cols >=80 zero) ----------------
__global__ void xconv(const float* __restrict__ x, __bf16* __restrict__ xb)
{
    int idx = blockIdx.x * 256 + threadIdx.x;       // (row, c8): row<B*T, c8<16
    int c8 = idx & 15, row = idx >> 4;
    bf16x8 r;
    if (c8 < 10) {
        const float4* p = reinterpret_cast<const float4*>(x + (size_t)row * 80 + c8 * 8);
        float4 u0 = p[0], u1 = p[1];
        r[0]=(__bf16)u0.x; r[1]=(__bf16)u0.y; r[2]=(__bf16)u0.z; r[3]=(__bf16)u0.w;
        r[4]=(__bf16)u1.x; r[5]=(__bf16)u1.y; r[6]=(__bf16)u1.z; r[7]=(__bf16)u1.w;
    } else {
#pragma unroll
        for (int i = 0; i < 8; ++i) r[i] = (__bf16)0.f;
    }
    *reinterpret_cast<bf16x8*>(xb + (size_t)row * 128 + c8 * 8) = r;
}

// ---------------- broadcast z2 sample into xb cols 80..111 for all t ----------------
__global__ void bcast_z2(const __bf16* __restrict__ z2sb, __bf16* __restrict__ xb)
{
    int idx = blockIdx.x * 256 + threadIdx.x;       // (b, g): g<4
    int g = idx & 3, b = idx >> 2;
    bf16x8 v = *reinterpret_cast<const bf16x8*>(z2sb + (size_t)b * 32 + g * 8);
#pragma unroll
    for (int t = 0; t < T_SZ; ++t)
        *reinterpret_cast<bf16x8*>(xb + ((size_t)b * T_SZ + t) * 128 + 80 + g * 8) = v;
}

// ---------------- async 16B global -> LDS ----------------
__device__ __forceinline__ void stage16(const __bf16* g, __bf16* l)
{
    __builtin_amdgcn_global_load_lds(
        (const __attribute__((address_space(1))) unsigned*)g,
        (__attribute__((address_space(3))) unsigned*)l, 16, 0, 0);
}

// ---------------- fused per-step LSTM-layer GEMM ----------------
// tile 128 rows x 128 cols, block 256 (4 waves), grid 1024 (bid = wgn*128+mid, mid%8 pins XCD).
// KT: kts actually computed; KTP: packed KT stride of this matrix; XKT: x-kts; TWOH: layer2;
// FIRST: t==0 (h_prev=0 -> prefix kts only; c_prev=0 -> no c read).
// A register-prefetched one phase ahead; B LDS double-buffered 2-kt phases.
template <int KT, int KTP, int XKT, int TWOH, int FIRST>
__global__ void __launch_bounds__(256, 4)
step_gemm(const __bf16* __restrict__ xb, int t,
          const __bf16* __restrict__ hA, const __bf16* __restrict__ hB,
          const __bf16* __restrict__ wpm, const float* __restrict__ bias,
          float* __restrict__ cbuf, __bf16* __restrict__ hout)
{
    constexpr int P = (KT + 1) / 2;
    __shared__ __align__(16) __bf16 Bs[4][4096];

    const int tid = threadIdx.x;
    const int w = tid >> 6, lane = tid & 63;
    const int r16 = lane & 15, kq = lane >> 4;
    const int mid = blockIdx.x & 127, wgn = blockIdx.x >> 7;
    const int rb = mid * 128 + w * 32;
    const __bf16* wpB = wpm + (size_t)wgn * KTP * 4096;

    const __bf16 *x0 = nullptr, *x1 = nullptr;
    if (XKT > 0) {
        x0 = xb + ((size_t)(rb + r16) * T_SZ + t) * 128;
        x1 = xb + ((size_t)(rb + 16 + r16) * T_SZ + t) * 128;
    }
    const __bf16* hA0 = hA + (size_t)(rb + r16) * 256;
    const __bf16* hA1 = hA + (size_t)(rb + 16 + r16) * 256;
    const __bf16* hB0 = TWOH ? hB + (size_t)(rb + r16) * 256 : nullptr;
    const __bf16* hB1 = TWOH ? hB + (size_t)(rb + 16 + r16) * 256 : nullptr;

    f32x4 acc[8][2];
#pragma unroll
    for (int nt = 0; nt < 8; ++nt)
#pragma unroll
        for (int m = 0; m < 2; ++m) acc[nt][m] = f32x4{0.f, 0.f, 0.f, 0.f};

    auto aptr = [&](int kt, int m) -> const __bf16* {
        if (kt < XKT) return (m ? x1 : x0) + kt * 32 + kq * 8;
        int kk = kt - XKT;
        if (!TWOH || kk < 8) return (m ? hA1 : hA0) + kk * 32 + kq * 8;
        return (m ? hB1 : hB0) + (kk - 8) * 32 + kq * 8;
    };
    auto loadPh = [&](int k0, bf16x8* a) {
        a[0] = *reinterpret_cast<const bf16x8*>(aptr(k0, 0));
        a[1] = *reinterpret_cast<const bf16x8*>(aptr(k0, 1));
        if (k0 + 1 < KT) {
            a[2] = *reinterpret_cast<const bf16x8*>(aptr(k0 + 1, 0));
            a[3] = *reinterpret_cast<const bf16x8*>(aptr(k0 + 1, 1));
        }
    };
    auto compPh = [&](int k0, const bf16x8* a) {
        {
            const __bf16* bp = &Bs[k0 & 3][lane * 8];
#pragma unroll
            for (int nt = 0; nt < 8; ++nt) {
                bf16x8 bv = *reinterpret_cast<const bf16x8*>(bp + nt * 512);
                acc[nt][0] = __builtin_amdgcn_mfma_f32_16x16x32_bf16(a[0], bv, acc[nt][0], 0, 0, 0);
                acc[nt][1] = __builtin_amdgcn_mfma_f32_16x16x32_bf16(a[1], bv, acc[nt][1], 0, 0, 0);
            }
        }
        if (k0 + 1 < KT) {
            const __bf16* bp = &Bs[(k0 + 1) & 3][lane * 8];
#pragma unroll
            for (int nt = 0; nt < 8; ++nt) {
                bf16x8 bv = *reinterpret_cast<const bf16x8*>(bp + nt * 512);
                acc[nt][0] = __builtin_amdgcn_mfma_f32_16x16x32_bf16(a[2], bv, acc[nt][0], 0, 0, 0);
                acc[nt][1] = __builtin_amdgcn_mfma_f32_16x16x32_bf16(a[3], bv, acc[nt][1], 0, 0, 0);
            }
        }
    };
    auto stageKt = [&](int kt) {
        const __bf16* g = wpB + (size_t)kt * 4096 + tid * 8;
        stage16(g, &Bs[kt & 3][tid * 8]);
        stage16(g + 2048, &Bs[kt & 3][2048 + tid * 8]);
    };

    bf16x8 aP[2][4];
    // prologue
    stageKt(0);
    if (KT > 1) stageKt(1);
    loadPh(0, aP[0]);
    __syncthreads();

#pragma unroll
    for (int p = 0; p < P; ++p) {
        const int ks = 2 * p + 2;
        if (ks < KT)     stageKt(ks);
        if (ks + 1 < KT) stageKt(ks + 1);
        if (ks < KT)     loadPh(ks, aP[(p + 1) & 1]);
        compPh(2 * p, aP[p & 1]);
        __syncthreads();
    }

    // ---- fused LSTM cell epilogue ----
    float bg[2][4];
#pragma unroll
    for (int hh = 0; hh < 2; ++hh)
#pragma unroll
        for (int gate = 0; gate < 4; ++gate)
            bg[hh][gate] = bias[gate * 256 + wgn * 32 + hh * 16 + r16];

#pragma unroll
    for (int m = 0; m < 2; ++m)
#pragma unroll
        for (int hh = 0; hh < 2; ++hh) {
            const int hcol = wgn * 32 + hh * 16 + r16;
            f32x4 zi = acc[0 + hh][m], zf = acc[2 + hh][m], zg = acc[4 + hh][m], zo = acc[6 + hh][m];
#pragma unroll
            for (int q = 0; q < 4; ++q) {
                int row = rb + m * 16 + kq * 4 + q;
                size_t off = (size_t)row * 256 + hcol;
                float cn;
                if (FIRST) {
                    cn = sigm(zi[q] + bg[hh][0]) * tanh_(zg[q] + bg[hh][2]);
                } else {
                    float co = cbuf[off];
                    cn = sigm(zf[q] + bg[hh][1]) * co
                       + sigm(zi[q] + bg[hh][0]) * tanh_(zg[q] + bg[hh][2]);
                }
                cbuf[off] = cn;
                hout[off] = (__bf16)(sigm(zo[q] + bg[hh][3]) * tanh_(cn));
            }
        }
}

// ---------------- MFMA head (unchanged) ----------------
__global__ void __launch_bounds__(128, 4)
head_mfma(const float* __restrict__ c1, const float* __restrict__ c2,
          const __bf16* __restrict__ hp, const float* __restrict__ mub,
          const float* __restrict__ lvb, const float* __restrict__ eps,
          float* __restrict__ omu, float* __restrict__ olv, float* __restrict__ osm,
          __bf16* __restrict__ osb)
{
    const int tid = threadIdx.x;
    const int w = tid >> 6, lane = tid & 63;
    const int r16 = lane & 15, kq = lane >> 4;
    const int rb = blockIdx.x * 64 + w * 32;

    f32x4 acc[4][2];
#pragma unroll
    for (int nt = 0; nt < 4; ++nt)
#pragma unroll
        for (int m = 0; m < 2; ++m) acc[nt][m] = f32x4{0.f, 0.f, 0.f, 0.f};

#pragma unroll
    for (int kt = 0; kt < 16; ++kt) {
        const float* cs = (kt < 8) ? c1 : c2;
        int k = (kt & 7) * 32 + kq * 8;
        bf16x8 a[2];
#pragma unroll
        for (int m = 0; m < 2; ++m) {
            const float* pr = cs + (size_t)(rb + m * 16 + r16) * 256 + k;
            float4 u0 = reinterpret_cast<const float4*>(pr)[0];
            float4 u1 = reinterpret_cast<const float4*>(pr)[1];
            a[m][0]=(__bf16)u0.x; a[m][1]=(__bf16)u0.y; a[m][2]=(__bf16)u0.z; a[m][3]=(__bf16)u0.w;
            a[m][4]=(__bf16)u1.x; a[m][5]=(__bf16)u1.y; a[m][6]=(__bf16)u1.z; a[m][7]=(__bf16)u1.w;
        }
        const __bf16* hb = hp + kt * 2048 + lane * 8;
#pragma unroll
        for (int nt = 0; nt < 4; ++nt) {
            bf16x8 bv = *reinterpret_cast<const bf16x8*>(hb + nt * 512);
            acc[nt][0] = __builtin_amdgcn_mfma_f32_16x16x32_bf16(a[0], bv, acc[nt][0], 0, 0, 0);
            acc[nt][1] = __builtin_amdgcn_mfma_f32_16x16x32_bf16(a[1], bv, acc[nt][1], 0, 0, 0);
        }
    }

#pragma unroll
    for (int m = 0; m < 2; ++m)
#pragma unroll
        for (int q = 0; q < 4; ++q) {
            int row = rb + m * 16 + kq * 4 + q;
#pragma unroll
            for (int z = 0; z < 2; ++z) {
                int zc = z * 16 + r16;
                float mu = acc[z][m][q] + mub[zc];
                float lv = acc[z + 2][m][q] + lvb[zc];
                int idx = row * 32 + zc;
                omu[idx] = mu;
                olv[idx] = lv;
                float s = fmaf(eps[idx], expf(0.5f * lv), mu);
                osm[idx] = s;
                if (osb) osb[idx] = (__bf16)s;
            }
        }
}

extern "C" void kernel_launch(void* const* d_in, const int* in_sizes, int n_in,
                              void* d_out, int out_size, void* d_ws, size_t ws_size,
                              hipStream_t stream)
{
    const float* x    = (const float*)d_in[0];
    const float* eps1 = (const float*)d_in[1];
    const float* eps2 = (const float*)d_in[2];
    const float* z2W1 = (const float*)d_in[3];
    const float* z2U1 = (const float*)d_in[4];
    const float* z2b1 = (const float*)d_in[5];
    const float* z2W2 = (const float*)d_in[6];
    const float* z2U2 = (const float*)d_in[7];
    const float* z2b2 = (const float*)d_in[8];
    const float* z1W1 = (const float*)d_in[9];
    const float* z1U1 = (const float*)d_in[10];
    const float* z1b1 = (const float*)d_in[11];
    const float* z1W2 = (const float*)d_in[12];
    const float* z1U2 = (const float*)d_in[13];
    const float* z1b2 = (const float*)d_in[14];
    const float* mu2W = (const float*)d_in[15];
    const float* mu2b = (const float*)d_in[16];
    const float* lv2W = (const float*)d_in[17];
    const float* lv2b = (const float*)d_in[18];
    const float* mu1W = (const float*)d_in[19];
    const float* mu1b = (const float*)d_in[20];
    const float* lv1W = (const float*)d_in[21];
    const float* lv1b = (const float*)d_in[22];

    char* ws = (char*)d_ws;
    __bf16* wp   = (__bf16*)ws;                        // 3.74 MB
    __bf16* z2sb = (__bf16*)(ws + 4194304);            // 1 MB
    __bf16* xb   = (__bf16*)(ws + 5242880);            // B*20*128 bf16 = 80 MB
    __bf16* h1a  = (__bf16*)(ws + 89128960);           // 8 MB each
    __bf16* h2a  = (__bf16*)(ws + 97517568);
    __bf16* h1b  = (__bf16*)(ws + 105906176);
    __bf16* h2b  = (__bf16*)(ws + 114294784);
    float*  c1   = (float*)(ws + 122683392);           // 16 MB each
    float*  c2   = (float*)(ws + 139460608);           // end 156,237,824

    __bf16* h1[2] = {h1a, h1b};
    __bf16* h2[2] = {h2a, h2b};

    float* out = (float*)d_out;
    const int BZ = B_SZ * 32;
    float* z1mu = out;           float* z1lv = out + BZ;     float* z1sm = out + 2 * BZ;
    float* z2mu = out + 3 * BZ;  float* z2lv = out + 4 * BZ; float* z2sm = out + 5 * BZ;

    xconv<<<B_SZ * T_SZ * 16 / 256, 256, 0, stream>>>(x, xb);
    prep_w<<<7296, 256, 0, stream>>>(z2W1, z2U1, z2W2, z2U2, z1W1, z1U1, z1W2, z1U2,
                                     mu2W, lv2W, mu1W, lv1W, wp);

    // ---- z2 branch ----
    // t = 0 (h=0, c=0): prefix-KT kernels, no memset needed
    step_gemm<3, 11, 3, 0, 1><<<1024, 256, 0, stream>>>(xb, 0, h1a, nullptr,
                                                        wp + OFF_L1Z2, z2b1, c1, h1[0]);
    step_gemm<8, 16, 0, 1, 1><<<1024, 256, 0, stream>>>(xb, 0, h1[0], h2a,
                                                        wp + OFF_L2Z2, z2b2, c2, h2[0]);
    for (int t = 1; t < T_SZ; ++t) {
        int cur = t & 1, prv = cur ^ 1;
        step_gemm<11, 11, 3, 0, 0><<<1024, 256, 0, stream>>>(xb, t, h1[prv], nullptr,
                                                             wp + OFF_L1Z2, z2b1, c1, h1[cur]);
        step_gemm<16, 16, 0, 1, 0><<<1024, 256, 0, stream>>>(xb, t, h1[cur], h2[prv],
                                                             wp + OFF_L2Z2, z2b2, c2, h2[cur]);
    }
    head_mfma<<<256, 128, 0, stream>>>(c1, c2, wp + OFF_HZ2, mu2b, lv2b, eps2,
                                       z2mu, z2lv, z2sm, z2sb);
    bcast_z2<<<B_SZ * 4 / 256, 256, 0, stream>>>(z2sb, xb);

    // ---- z1 branch ----
    step_gemm<4, 12, 4, 0, 1><<<1024, 256, 0, stream>>>(xb, 0, h1a, nullptr,
                                                        wp + OFF_L1Z1, z1b1, c1, h1[0]);
    step_gemm<8, 16, 0, 1, 1><<<1024, 256, 0, stream>>>(xb, 0, h1[0], h2a,
                                                        wp + OFF_L2Z1, z1b2, c2, h2[0]);
    for (int t = 1; t < T_SZ; ++t) {
        int cur = t & 1, prv = cur ^ 1;
        step_gemm<12, 12, 4, 0, 0><<<1024, 256, 0, stream>>>(xb, t, h1[prv], nullptr,
                                                             wp + OFF_L1Z1, z1b1, c1, h1[cur]);
        step_gemm<16, 16, 0, 1, 0><<<1024, 256, 0, stream>>>(xb, t, h1[cur], h2[prv],
                                                             wp + OFF_L2Z1, z1b2, c2, h2[cur]);
    }
    head_mfma<<<256, 128, 0, stream>>>(c1, c2, wp + OFF_HZ1, mu1b, lv1b, eps1,
                                       z1mu, z1lv, z1sm, nullptr);
}

// Round 6
// 2223.028 us; speedup vs baseline: 3.3750x; 1.0674x over previous
//
#include <hip/hip_runtime.h>
#include <hip/hip_bf16.h>

#define B_SZ 16384
#define T_SZ 20

typedef __attribute__((ext_vector_type(8))) __bf16 bf16x8;
typedef __attribute__((ext_vector_type(4))) float f32x4;

__device__ __forceinline__ float sigm(float x){ return 1.f/(1.f+__expf(-x)); }
__device__ __forceinline__ float tanh_(float x){ return 1.f-2.f/(__expf(2.f*x)+1.f); }

// packed weight element offsets (bf16 elements)
#define OFF_L1Z2 0
#define OFF_L2Z2 360448
#define OFF_L1Z1 884736
#define OFF_L2Z1 1277952
#define OFF_HZ2  1802240
#define OFF_HZ1  1835008
#define WP_TOT   1867776

// ---------------- weight prep (unchanged) ----------------
__global__ void prep_w(const float* __restrict__ W0, const float* __restrict__ U0,
                       const float* __restrict__ W1, const float* __restrict__ U1,
                       const float* __restrict__ W2, const float* __restrict__ U2,
                       const float* __restrict__ W3, const float* __restrict__ U3,
                       const float* __restrict__ muW2, const float* __restrict__ lvW2,
                       const float* __restrict__ muW1, const float* __restrict__ lvW1,
                       __bf16* __restrict__ wp)
{
    int idx = blockIdx.x * 256 + threadIdx.x;
    if (idx >= WP_TOT) return;
    if (idx < OFF_HZ2) {
        const float *W, *U;
        int Fx, Kx, KT, local;
        if (idx < OFF_L2Z2)      { W = W0; U = U0; Fx = 80;  Kx = 96;  KT = 11; local = idx; }
        else if (idx < OFF_L1Z1) { W = W1; U = U1; Fx = 256; Kx = 256; KT = 16; local = idx - OFF_L2Z2; }
        else if (idx < OFF_L2Z1) { W = W2; U = U2; Fx = 112; Kx = 128; KT = 12; local = idx - OFF_L1Z1; }
        else                     { W = W3; U = U3; Fx = 256; Kx = 256; KT = 16; local = idx - OFF_L2Z1; }
        int jj = local & 7, lane = (local >> 3) & 63, nt8 = (local >> 9) & 7, rest = local >> 12;
        int kt = rest % KT, wgn = rest / KT;
        int gate = nt8 >> 1, hh = nt8 & 1;
        int n = gate * 256 + wgn * 32 + hh * 16 + (lane & 15);
        int k = kt * 32 + ((lane >> 4) << 3) + jj;
        float v = (k < Fx) ? W[k * 1024 + n] : (k < Kx ? 0.f : U[(k - Kx) * 1024 + n]);
        wp[idx] = (__bf16)v;
    } else {
        int base = (idx < OFF_HZ1) ? OFF_HZ2 : OFF_HZ1;
        const float* mw = (idx < OFF_HZ1) ? muW2 : muW1;
        const float* lw = (idx < OFF_HZ1) ? lvW2 : lvW1;
        int local = idx - base;
        int jj = local & 7, lane = (local >> 3) & 63, nt = (local >> 9) & 3, kt = local >> 11;
        int k = kt * 32 + ((lane >> 4) << 3) + jj;
        int c16 = lane & 15;
        float v = (nt < 2) ? mw[k * 32 + nt * 16 + c16] : lw[k * 32 + (nt - 2) * 16 + c16];
        wp[idx] = (__bf16)v;
    }
}

// ---------------- x fp32 -> xb bf16 [B][T][128] (cols >=80 zero) ----------------
__global__ void xconv(const float* __restrict__ x, __bf16* __restrict__ xb)
{
    int idx = blockIdx.x * 256 + threadIdx.x;
    int c8 = idx & 15, row = idx >> 4;
    bf16x8 r;
    if (c8 < 10) {
        const float4* p = reinterpret_cast<const float4*>(x + (size_t)row * 80 + c8 * 8);
        float4 u0 = p[0], u1 = p[1];
        r[0]=(__bf16)u0.x; r[1]=(__bf16)u0.y; r[2]=(__bf16)u0.z; r[3]=(__bf16)u0.w;
        r[4]=(__bf16)u1.x; r[5]=(__bf16)u1.y; r[6]=(__bf16)u1.z; r[7]=(__bf16)u1.w;
    } else {
#pragma unroll
        for (int i = 0; i < 8; ++i) r[i] = (__bf16)0.f;
    }
    *reinterpret_cast<bf16x8*>(xb + (size_t)row * 128 + c8 * 8) = r;
}

// ---------------- broadcast z2 sample into xb cols 80..111 for all t ----------------
__global__ void bcast_z2(const __bf16* __restrict__ z2sb, __bf16* __restrict__ xb)
{
    int idx = blockIdx.x * 256 + threadIdx.x;
    int g = idx & 3, b = idx >> 2;
    bf16x8 v = *reinterpret_cast<const bf16x8*>(z2sb + (size_t)b * 32 + g * 8);
#pragma unroll
    for (int t = 0; t < T_SZ; ++t)
        *reinterpret_cast<bf16x8*>(xb + ((size_t)b * T_SZ + t) * 128 + 80 + g * 8) = v;
}

// ---------------- async 16B global -> LDS ----------------
__device__ __forceinline__ void stage16(const __bf16* g, __bf16* l)
{
    __builtin_amdgcn_global_load_lds(
        (const __attribute__((address_space(1))) unsigned*)g,
        (__attribute__((address_space(3))) unsigned*)l, 16, 0, 0);
}

// ---------------- fused per-step LSTM-layer GEMM (counted-vmcnt ring pipeline) ----------------
// tile 128 rows x 128 cols, block 256 (4 waves), grid 1024 (bid = wgn*128+mid, mid%8 pins XCD).
// 1-kt phases over Bs[4] ring; B staged 2 kt ahead (global_load_lds); A in 3-slot reg ring,
// loaded 2 kt ahead. Per phase: vmcnt(N) with N = ops of 2 newest iterations (8/4/0) + raw
// s_barrier — loads stay in flight across barriers (T3+T4), never drain to 0 mid-loop.
template <int KT, int KTP, int XKT, int TWOH, int FIRST>
__global__ void __launch_bounds__(256, 4)
step_gemm(const __bf16* __restrict__ xb, int t,
          const __bf16* __restrict__ hA, const __bf16* __restrict__ hB,
          const __bf16* __restrict__ wpm, const float* __restrict__ bias,
          float* __restrict__ cbuf, __bf16* __restrict__ hout)
{
    __shared__ __align__(16) __bf16 Bs[4][4096];

    const int tid = threadIdx.x;
    const int w = tid >> 6, lane = tid & 63;
    const int r16 = lane & 15, kq = lane >> 4;
    const int mid = blockIdx.x & 127, wgn = blockIdx.x >> 7;
    const int rb = mid * 128 + w * 32;
    const __bf16* wpB = wpm + (size_t)wgn * KTP * 4096;

    const __bf16 *x0 = nullptr, *x1 = nullptr;
    if (XKT > 0) {
        x0 = xb + ((size_t)(rb + r16) * T_SZ + t) * 128 + kq * 8;
        x1 = xb + ((size_t)(rb + 16 + r16) * T_SZ + t) * 128 + kq * 8;
    }
    const __bf16* hA0 = hA + (size_t)(rb + r16) * 256 + kq * 8;
    const __bf16* hA1 = hA + (size_t)(rb + 16 + r16) * 256 + kq * 8;
    const __bf16 *hB0 = nullptr, *hB1 = nullptr;
    if (TWOH) {
        hB0 = hB + (size_t)(rb + r16) * 256 + kq * 8;
        hB1 = hB + (size_t)(rb + 16 + r16) * 256 + kq * 8;
    }

    f32x4 acc[8][2];
#pragma unroll
    for (int nt = 0; nt < 8; ++nt)
#pragma unroll
        for (int m = 0; m < 2; ++m) acc[nt][m] = f32x4{0.f, 0.f, 0.f, 0.f};

    bf16x8 aR[3][2];

    auto ap = [&](int kt, int m) -> const __bf16* {
        if (XKT > 0 && kt < XKT) return (m ? x1 : x0) + kt * 32;
        int kk = kt - XKT;
        if (!TWOH || kk < 8) return (m ? hA1 : hA0) + kk * 32;
        return (m ? hB1 : hB0) + (kk - 8) * 32;
    };

#define STG(K) { const __bf16* g_ = wpB + (size_t)(K) * 4096 + tid * 8;            \
                 stage16(g_, &Bs[(K) & 3][tid * 8]);                               \
                 stage16(g_ + 2048, &Bs[(K) & 3][2048 + tid * 8]); }
#define LDA(K) { aR[(K) % 3][0] = *reinterpret_cast<const bf16x8*>(ap((K), 0));    \
                 aR[(K) % 3][1] = *reinterpret_cast<const bf16x8*>(ap((K), 1)); }
#define CMP(K) { const __bf16* bp_ = &Bs[(K) & 3][lane * 8];                       \
    _Pragma("unroll") for (int nt = 0; nt < 8; ++nt) {                             \
        bf16x8 bv_ = *reinterpret_cast<const bf16x8*>(bp_ + nt * 512);             \
        acc[nt][0] = __builtin_amdgcn_mfma_f32_16x16x32_bf16(aR[(K)%3][0], bv_, acc[nt][0], 0, 0, 0); \
        acc[nt][1] = __builtin_amdgcn_mfma_f32_16x16x32_bf16(aR[(K)%3][1], bv_, acc[nt][1], 0, 0, 0); } }
#define PH(K) if constexpr ((K) < KT) {                                            \
    __builtin_amdgcn_sched_barrier(0);                                             \
    if constexpr ((K) + 2 < KT) { STG((K) + 2); LDA((K) + 2); }                    \
    { constexpr int cnt_ = 4 * (((K) + 1 < KT) ? 1 : 0) + 4 * (((K) + 2 < KT) ? 1 : 0); \
      asm volatile("s_waitcnt vmcnt(%0)" :: "n"(cnt_) : "memory"); }               \
    __builtin_amdgcn_s_barrier();                                                  \
    __builtin_amdgcn_sched_barrier(0);                                             \
    CMP(K); }

    // prologue: iters -2,-1
    STG(0); LDA(0);
    if constexpr (KT > 1) { STG(1); LDA(1); }

    PH(0)  PH(1)  PH(2)  PH(3)  PH(4)  PH(5)  PH(6)  PH(7)
    PH(8)  PH(9)  PH(10) PH(11) PH(12) PH(13) PH(14) PH(15)

#undef STG
#undef LDA
#undef CMP
#undef PH

    // ---- fused LSTM cell epilogue (bias loaded here, after the counted-vmcnt loop) ----
    float bg[2][4];
#pragma unroll
    for (int hh = 0; hh < 2; ++hh)
#pragma unroll
        for (int gate = 0; gate < 4; ++gate)
            bg[hh][gate] = bias[gate * 256 + wgn * 32 + hh * 16 + r16];

#pragma unroll
    for (int m = 0; m < 2; ++m)
#pragma unroll
        for (int hh = 0; hh < 2; ++hh) {
            const int hcol = wgn * 32 + hh * 16 + r16;
            f32x4 zi = acc[0 + hh][m], zf = acc[2 + hh][m], zg = acc[4 + hh][m], zo = acc[6 + hh][m];
#pragma unroll
            for (int q = 0; q < 4; ++q) {
                int row = rb + m * 16 + kq * 4 + q;
                size_t off = (size_t)row * 256 + hcol;
                float cn;
                if (FIRST) {
                    cn = sigm(zi[q] + bg[hh][0]) * tanh_(zg[q] + bg[hh][2]);
                } else {
                    float co = cbuf[off];
                    cn = sigm(zf[q] + bg[hh][1]) * co
                       + sigm(zi[q] + bg[hh][0]) * tanh_(zg[q] + bg[hh][2]);
                }
                cbuf[off] = cn;
                hout[off] = (__bf16)(sigm(zo[q] + bg[hh][3]) * tanh_(cn));
            }
        }
}

// ---------------- MFMA head (unchanged) ----------------
__global__ void __launch_bounds__(128, 4)
head_mfma(const float* __restrict__ c1, const float* __restrict__ c2,
          const __bf16* __restrict__ hp, const float* __restrict__ mub,
          const float* __restrict__ lvb, const float* __restrict__ eps,
          float* __restrict__ omu, float* __restrict__ olv, float* __restrict__ osm,
          __bf16* __restrict__ osb)
{
    const int tid = threadIdx.x;
    const int w = tid >> 6, lane = tid & 63;
    const int r16 = lane & 15, kq = lane >> 4;
    const int rb = blockIdx.x * 64 + w * 32;

    f32x4 acc[4][2];
#pragma unroll
    for (int nt = 0; nt < 4; ++nt)
#pragma unroll
        for (int m = 0; m < 2; ++m) acc[nt][m] = f32x4{0.f, 0.f, 0.f, 0.f};

#pragma unroll
    for (int kt = 0; kt < 16; ++kt) {
        const float* cs = (kt < 8) ? c1 : c2;
        int k = (kt & 7) * 32 + kq * 8;
        bf16x8 a[2];
#pragma unroll
        for (int m = 0; m < 2; ++m) {
            const float* pr = cs + (size_t)(rb + m * 16 + r16) * 256 + k;
            float4 u0 = reinterpret_cast<const float4*>(pr)[0];
            float4 u1 = reinterpret_cast<const float4*>(pr)[1];
            a[m][0]=(__bf16)u0.x; a[m][1]=(__bf16)u0.y; a[m][2]=(__bf16)u0.z; a[m][3]=(__bf16)u0.w;
            a[m][4]=(__bf16)u1.x; a[m][5]=(__bf16)u1.y; a[m][6]=(__bf16)u1.z; a[m][7]=(__bf16)u1.w;
        }
        const __bf16* hb = hp + kt * 2048 + lane * 8;
#pragma unroll
        for (int nt = 0; nt < 4; ++nt) {
            bf16x8 bv = *reinterpret_cast<const bf16x8*>(hb + nt * 512);
            acc[nt][0] = __builtin_amdgcn_mfma_f32_16x16x32_bf16(a[0], bv, acc[nt][0], 0, 0, 0);
            acc[nt][1] = __builtin_amdgcn_mfma_f32_16x16x32_bf16(a[1], bv, acc[nt][1], 0, 0, 0);
        }
    }

#pragma unroll
    for (int m = 0; m < 2; ++m)
#pragma unroll
        for (int q = 0; q < 4; ++q) {
            int row = rb + m * 16 + kq * 4 + q;
#pragma unroll
            for (int z = 0; z < 2; ++z) {
                int zc = z * 16 + r16;
                float mu = acc[z][m][q] + mub[zc];
                float lv = acc[z + 2][m][q] + lvb[zc];
                int idx = row * 32 + zc;
                omu[idx] = mu;
                olv[idx] = lv;
                float s = fmaf(eps[idx], expf(0.5f * lv), mu);
                osm[idx] = s;
                if (osb) osb[idx] = (__bf16)s;
            }
        }
}

extern "C" void kernel_launch(void* const* d_in, const int* in_sizes, int n_in,
                              void* d_out, int out_size, void* d_ws, size_t ws_size,
                              hipStream_t stream)
{
    const float* x    = (const float*)d_in[0];
    const float* eps1 = (const float*)d_in[1];
    const float* eps2 = (const float*)d_in[2];
    const float* z2W1 = (const float*)d_in[3];
    const float* z2U1 = (const float*)d_in[4];
    const float* z2b1 = (const float*)d_in[5];
    const float* z2W2 = (const float*)d_in[6];
    const float* z2U2 = (const float*)d_in[7];
    const float* z2b2 = (const float*)d_in[8];
    const float* z1W1 = (const float*)d_in[9];
    const float* z1U1 = (const float*)d_in[10];
    const float* z1b1 = (const float*)d_in[11];
    const float* z1W2 = (const float*)d_in[12];
    const float* z1U2 = (const float*)d_in[13];
    const float* z1b2 = (const float*)d_in[14];
    const float* mu2W = (const float*)d_in[15];
    const float* mu2b = (const float*)d_in[16];
    const float* lv2W = (const float*)d_in[17];
    const float* lv2b = (const float*)d_in[18];
    const float* mu1W = (const float*)d_in[19];
    const float* mu1b = (const float*)d_in[20];
    const float* lv1W = (const float*)d_in[21];
    const float* lv1b = (const float*)d_in[22];

    char* ws = (char*)d_ws;
    __bf16* wp   = (__bf16*)ws;                        // 3.74 MB
    __bf16* z2sb = (__bf16*)(ws + 4194304);            // 1 MB
    __bf16* xb   = (__bf16*)(ws + 5242880);            // 80 MB
    __bf16* h1a  = (__bf16*)(ws + 89128960);           // 8 MB each
    __bf16* h2a  = (__bf16*)(ws + 97517568);
    __bf16* h1b  = (__bf16*)(ws + 105906176);
    __bf16* h2b  = (__bf16*)(ws + 114294784);
    float*  c1   = (float*)(ws + 122683392);           // 16 MB each
    float*  c2   = (float*)(ws + 139460608);           // end 156,237,824

    __bf16* h1[2] = {h1a, h1b};
    __bf16* h2[2] = {h2a, h2b};

    float* out = (float*)d_out;
    const int BZ = B_SZ * 32;
    float* z1mu = out;           float* z1lv = out + BZ;     float* z1sm = out + 2 * BZ;
    float* z2mu = out + 3 * BZ;  float* z2lv = out + 4 * BZ; float* z2sm = out + 5 * BZ;

    xconv<<<B_SZ * T_SZ * 16 / 256, 256, 0, stream>>>(x, xb);
    prep_w<<<7296, 256, 0, stream>>>(z2W1, z2U1, z2W2, z2U2, z1W1, z1U1, z1W2, z1U2,
                                     mu2W, lv2W, mu1W, lv1W, wp);

    // ---- z2 branch ----
    step_gemm<3, 11, 3, 0, 1><<<1024, 256, 0, stream>>>(xb, 0, h1a, nullptr,
                                                        wp + OFF_L1Z2, z2b1, c1, h1[0]);
    step_gemm<8, 16, 0, 1, 1><<<1024, 256, 0, stream>>>(xb, 0, h1[0], h2a,
                                                        wp + OFF_L2Z2, z2b2, c2, h2[0]);
    for (int t = 1; t < T_SZ; ++t) {
        int cur = t & 1, prv = cur ^ 1;
        step_gemm<11, 11, 3, 0, 0><<<1024, 256, 0, stream>>>(xb, t, h1[prv], nullptr,
                                                             wp + OFF_L1Z2, z2b1, c1, h1[cur]);
        step_gemm<16, 16, 0, 1, 0><<<1024, 256, 0, stream>>>(xb, t, h1[cur], h2[prv],
                                                             wp + OFF_L2Z2, z2b2, c2, h2[cur]);
    }
    head_mfma<<<256, 128, 0, stream>>>(c1, c2, wp + OFF_HZ2, mu2b, lv2b, eps2,
                                       z2mu, z2lv, z2sm, z2sb);
    bcast_z2<<<B_SZ * 4 / 256, 256, 0, stream>>>(z2sb, xb);

    // ---- z1 branch ----
    step_gemm<4, 12, 4, 0, 1><<<1024, 256, 0, stream>>>(xb, 0, h1a, nullptr,
                                                        wp + OFF_L1Z1, z1b1, c1, h1[0]);
    step_gemm<8, 16, 0, 1, 1><<<1024, 256, 0, stream>>>(xb, 0, h1[0], h2a,
                                                        wp + OFF_L2Z1, z1b2, c2, h2[0]);
    for (int t = 1; t < T_SZ; ++t) {
        int cur = t & 1, prv = cur ^ 1;
        step_gemm<12, 12, 4, 0, 0><<<1024, 256, 0, stream>>>(xb, t, h1[prv], nullptr,
                                                             wp + OFF_L1Z1, z1b1, c1, h1[cur]);
        step_gemm<16, 16, 0, 1, 0><<<1024, 256, 0, stream>>>(xb, t, h1[cur], h2[prv],
                                                             wp + OFF_L2Z1, z1b2, c2, h2[cur]);
    }
    head_mfma<<<256, 128, 0, stream>>>(c1, c2, wp + OFF_HZ1, mu1b, lv1b, eps1,
                                       z1mu, z1lv, z1sm, nullptr);
}

// Round 7
// 2144.218 us; speedup vs baseline: 3.4991x; 1.0368x over previous
//
#include <hip/hip_runtime.h>
#include <hip/hip_bf16.h>

#define B_SZ 16384
#define T_SZ 20

typedef __attribute__((ext_vector_type(8))) __bf16 bf16x8;
typedef __attribute__((ext_vector_type(4))) float f32x4;

__device__ __forceinline__ float sigm(float x){ return 1.f/(1.f+__expf(-x)); }
__device__ __forceinline__ float tanh_(float x){ return 1.f-2.f/(__expf(2.f*x)+1.f); }

// packed weight element offsets (bf16 elements) — totals unchanged (4*KT*16*512 = 32768*KT)
#define OFF_L1Z2 0
#define OFF_L2Z2 360448
#define OFF_L1Z1 884736
#define OFF_L2Z1 1277952
#define OFF_HZ2  1802240
#define OFF_HZ1  1835008
#define WP_TOT   1867776

// ---------------- weight prep ----------------
// LSTM mats (NEW 4-wgn layout): elem idx = ((wgn*KT + kt)*16 + nt16)*512 + lane*8 + jj
//   gate = nt16&3, hh = nt16>>2 ; n = gate*256 + wgn*64 + hh*16 + (lane&15)
//   k = kt*32 + (lane>>4)*8 + jj ; v = k<Fx ? W[k][n] : (k<Kx ? 0 : U[k-Kx][n])
// head mats: unchanged: idx = (kt*4 + nt)*512 + lane*8 + jj
__global__ void prep_w(const float* __restrict__ W0, const float* __restrict__ U0,
                       const float* __restrict__ W1, const float* __restrict__ U1,
                       const float* __restrict__ W2, const float* __restrict__ U2,
                       const float* __restrict__ W3, const float* __restrict__ U3,
                       const float* __restrict__ muW2, const float* __restrict__ lvW2,
                       const float* __restrict__ muW1, const float* __restrict__ lvW1,
                       __bf16* __restrict__ wp)
{
    int idx = blockIdx.x * 256 + threadIdx.x;
    if (idx >= WP_TOT) return;
    if (idx < OFF_HZ2) {
        const float *W, *U;
        int Fx, Kx, KT, local;
        if (idx < OFF_L2Z2)      { W = W0; U = U0; Fx = 80;  Kx = 96;  KT = 11; local = idx; }
        else if (idx < OFF_L1Z1) { W = W1; U = U1; Fx = 256; Kx = 256; KT = 16; local = idx - OFF_L2Z2; }
        else if (idx < OFF_L2Z1) { W = W2; U = U2; Fx = 112; Kx = 128; KT = 12; local = idx - OFF_L1Z1; }
        else                     { W = W3; U = U3; Fx = 256; Kx = 256; KT = 16; local = idx - OFF_L2Z1; }
        int jj = local & 7, lane = (local >> 3) & 63, nt16 = (local >> 9) & 15, rest = local >> 13;
        int kt = rest % KT, wgn = rest / KT;
        int gate = nt16 & 3, hh = nt16 >> 2;
        int n = gate * 256 + wgn * 64 + hh * 16 + (lane & 15);
        int k = kt * 32 + ((lane >> 4) << 3) + jj;
        float v = (k < Fx) ? W[k * 1024 + n] : (k < Kx ? 0.f : U[(k - Kx) * 1024 + n]);
        wp[idx] = (__bf16)v;
    } else {
        int base = (idx < OFF_HZ1) ? OFF_HZ2 : OFF_HZ1;
        const float* mw = (idx < OFF_HZ1) ? muW2 : muW1;
        const float* lw = (idx < OFF_HZ1) ? lvW2 : lvW1;
        int local = idx - base;
        int jj = local & 7, lane = (local >> 3) & 63, nt = (local >> 9) & 3, kt = local >> 11;
        int k = kt * 32 + ((lane >> 4) << 3) + jj;
        int c16 = lane & 15;
        float v = (nt < 2) ? mw[k * 32 + nt * 16 + c16] : lw[k * 32 + (nt - 2) * 16 + c16];
        wp[idx] = (__bf16)v;
    }
}

// ---------------- x fp32 -> xb bf16 [B][T][128] (cols >=80 zero) ----------------
__global__ void xconv(const float* __restrict__ x, __bf16* __restrict__ xb)
{
    int idx = blockIdx.x * 256 + threadIdx.x;
    int c8 = idx & 15, row = idx >> 4;
    bf16x8 r;
    if (c8 < 10) {
        const float4* p = reinterpret_cast<const float4*>(x + (size_t)row * 80 + c8 * 8);
        float4 u0 = p[0], u1 = p[1];
        r[0]=(__bf16)u0.x; r[1]=(__bf16)u0.y; r[2]=(__bf16)u0.z; r[3]=(__bf16)u0.w;
        r[4]=(__bf16)u1.x; r[5]=(__bf16)u1.y; r[6]=(__bf16)u1.z; r[7]=(__bf16)u1.w;
    } else {
#pragma unroll
        for (int i = 0; i < 8; ++i) r[i] = (__bf16)0.f;
    }
    *reinterpret_cast<bf16x8*>(xb + (size_t)row * 128 + c8 * 8) = r;
}

// ---------------- broadcast z2 sample into xb cols 80..111 for all t ----------------
__global__ void bcast_z2(const __bf16* __restrict__ z2sb, __bf16* __restrict__ xb)
{
    int idx = blockIdx.x * 256 + threadIdx.x;
    int g = idx & 3, b = idx >> 2;
    bf16x8 v = *reinterpret_cast<const bf16x8*>(z2sb + (size_t)b * 32 + g * 8);
#pragma unroll
    for (int t = 0; t < T_SZ; ++t)
        *reinterpret_cast<bf16x8*>(xb + ((size_t)b * T_SZ + t) * 128 + 80 + g * 8) = v;
}

// ---------------- async 16B global -> LDS (per-lane global src, lane-linear LDS dest) ----------------
__device__ __forceinline__ void stage16(const __bf16* g, __bf16* l)
{
    __builtin_amdgcn_global_load_lds(
        (const __attribute__((address_space(1))) unsigned*)g,
        (__attribute__((address_space(3))) unsigned*)l, 16, 0, 0);
}

// ---------------- fused per-step LSTM-layer GEMM ----------------
// wg tile 256 rows x 256 packed cols; grid 256 (bid = wgn*64 + mid; mid%8 pins XCD; A row-band
// producer/consumer share XCD). block 512 = 8 waves as (wr 0..1, wc 0..3): wave = 128 rows x 64 cols
// (nr=8, nc=4 -> 384 B operand / MFMA).  A staged in LDS ring-3 ([256][32] lane-linear via
// global_load_lds, per-lane global src); B direct global->VGPR ring-3, loaded 2 phases ahead.
// Counted vmcnt per phase = 2 (A-stage k+1) + 4 (B k+2); single barrier per phase; ring-3 makes
// the stage-write vs 2-phase-old reads race-free.
template <int KT, int KTP, int XKT, int TWOH, int FIRST>
__global__ void __launch_bounds__(512, 2)
step_gemm(const __bf16* __restrict__ xb, int t,
          const __bf16* __restrict__ hA, const __bf16* __restrict__ hB,
          const __bf16* __restrict__ wpm, const float* __restrict__ bias,
          float* __restrict__ cbuf, __bf16* __restrict__ hout)
{
    __shared__ __align__(16) __bf16 As[3][8192];   // 3 x 16 KB

    const int tid = threadIdx.x;
    const int w = tid >> 6, lane = tid & 63;
    const int r16 = lane & 15, kq = lane >> 4;
    const int wr = w >> 2, wc = w & 3;
    const int mid = blockIdx.x & 63, wgn = blockIdx.x >> 6;
    const int rb = mid * 256;
    const __bf16* wpB = wpm + (size_t)wgn * KTP * 8192;
    const __bf16* pBW = wpB + wc * 2048 + lane * 8;      // B frag base (this wave's 4 nt-blocks)

    // A staging: wave w covers tile rows [w*32, w*32+32), 2 instrs x (16 rows x 32 k)
    const int srow0 = rb + w * 32 + (lane >> 2);
    const int ksub  = (lane & 3) * 8;
    const __bf16* pA0 = hA + (size_t)srow0 * 256 + ksub;
    const __bf16* pA1 = hA + (size_t)(srow0 + 16) * 256 + ksub;
    const __bf16* px0 = (XKT > 0) ? xb + ((size_t)srow0 * T_SZ + t) * 128 + ksub : pA0;
    const __bf16* px1 = (XKT > 0) ? xb + ((size_t)(srow0 + 16) * T_SZ + t) * 128 + ksub : pA1;
    const __bf16* pH0 = TWOH ? hB + (size_t)srow0 * 256 + ksub : pA0;
    const __bf16* pH1 = TWOH ? hB + (size_t)(srow0 + 16) * 256 + ksub : pA1;

    f32x4 acc[4][8];
#pragma unroll
    for (int g = 0; g < 4; ++g)
#pragma unroll
        for (int m = 0; m < 8; ++m) acc[g][m] = f32x4{0.f, 0.f, 0.f, 0.f};

    bf16x8 bR[3][4];

#define ASRC(K, P0, PA, PH_) \
    ((K) < XKT ? (P0) + (K) * 32 \
               : ((!TWOH || ((K) - XKT) < 8) ? (PA) + ((K) - XKT) * 32 \
                                             : (PH_) + ((K) - XKT - 8) * 32))
#define STG_A(K) { stage16(ASRC(K, px0, pA0, pH0), &As[(K) % 3][w * 1024]); \
                   stage16(ASRC(K, px1, pA1, pH1), &As[(K) % 3][w * 1024 + 512]); }
#define LDB(K) { _Pragma("unroll") for (int nt = 0; nt < 4; ++nt) \
                   bR[(K) % 3][nt] = *reinterpret_cast<const bf16x8*>(pBW + (size_t)(K) * 8192 + nt * 512); }
#define CMP(K) { const __bf16* ab_ = &As[(K) % 3][(wr * 128 + r16) * 32 + kq * 8]; \
    bf16x8 a_[8]; \
    _Pragma("unroll") for (int m = 0; m < 8; ++m) \
        a_[m] = *reinterpret_cast<const bf16x8*>(ab_ + m * 512); \
    _Pragma("unroll") for (int m = 0; m < 8; ++m) \
        _Pragma("unroll") for (int g = 0; g < 4; ++g) \
            acc[g][m] = __builtin_amdgcn_mfma_f32_16x16x32_bf16(a_[m], bR[(K) % 3][g], acc[g][m], 0, 0, 0); }
#define PH(K) if constexpr ((K) < KT) { \
    __builtin_amdgcn_sched_barrier(0); \
    if constexpr ((K) + 1 < KT) STG_A((K) + 1); \
    if constexpr ((K) + 2 < KT) LDB((K) + 2); \
    { constexpr int c_ = 2 * (((K) + 1 < KT) ? 1 : 0) + 4 * (((K) + 2 < KT) ? 1 : 0); \
      asm volatile("s_waitcnt vmcnt(%0)" :: "n"(c_) : "memory"); } \
    __builtin_amdgcn_s_barrier(); \
    __builtin_amdgcn_sched_barrier(0); \
    CMP(K); }

    // prologue
    STG_A(0); LDB(0);
    if constexpr (KT > 1) LDB(1);

    PH(0)  PH(1)  PH(2)  PH(3)  PH(4)  PH(5)  PH(6)  PH(7)
    PH(8)  PH(9)  PH(10) PH(11) PH(12) PH(13) PH(14) PH(15)

#undef ASRC
#undef STG_A
#undef LDB
#undef CMP
#undef PH

    // ---- fused LSTM cell epilogue (wave owns 16 h-cols, all 4 gates lane-local) ----
    const int hcol = wgn * 64 + wc * 16 + r16;
    float bg[4];
#pragma unroll
    for (int g = 0; g < 4; ++g) bg[g] = bias[g * 256 + hcol];

#pragma unroll
    for (int m = 0; m < 8; ++m) {
        f32x4 zi = acc[0][m], zf = acc[1][m], zg = acc[2][m], zo = acc[3][m];
#pragma unroll
        for (int q = 0; q < 4; ++q) {
            int row = rb + wr * 128 + m * 16 + kq * 4 + q;
            size_t off = (size_t)row * 256 + hcol;
            float cn;
            if (FIRST) {
                cn = sigm(zi[q] + bg[0]) * tanh_(zg[q] + bg[2]);
            } else {
                float co = cbuf[off];
                cn = sigm(zf[q] + bg[1]) * co + sigm(zi[q] + bg[0]) * tanh_(zg[q] + bg[2]);
            }
            cbuf[off] = cn;
            hout[off] = (__bf16)(sigm(zo[q] + bg[3]) * tanh_(cn));
        }
    }
}

// ---------------- MFMA head (unchanged) ----------------
__global__ void __launch_bounds__(128, 4)
head_mfma(const float* __restrict__ c1, const float* __restrict__ c2,
          const __bf16* __restrict__ hp, const float* __restrict__ mub,
          const float* __restrict__ lvb, const float* __restrict__ eps,
          float* __restrict__ omu, float* __restrict__ olv, float* __restrict__ osm,
          __bf16* __restrict__ osb)
{
    const int tid = threadIdx.x;
    const int w = tid >> 6, lane = tid & 63;
    const int r16 = lane & 15, kq = lane >> 4;
    const int rb = blockIdx.x * 64 + w * 32;

    f32x4 acc[4][2];
#pragma unroll
    for (int nt = 0; nt < 4; ++nt)
#pragma unroll
        for (int m = 0; m < 2; ++m) acc[nt][m] = f32x4{0.f, 0.f, 0.f, 0.f};

#pragma unroll
    for (int kt = 0; kt < 16; ++kt) {
        const float* cs = (kt < 8) ? c1 : c2;
        int k = (kt & 7) * 32 + kq * 8;
        bf16x8 a[2];
#pragma unroll
        for (int m = 0; m < 2; ++m) {
            const float* pr = cs + (size_t)(rb + m * 16 + r16) * 256 + k;
            float4 u0 = reinterpret_cast<const float4*>(pr)[0];
            float4 u1 = reinterpret_cast<const float4*>(pr)[1];
            a[m][0]=(__bf16)u0.x; a[m][1]=(__bf16)u0.y; a[m][2]=(__bf16)u0.z; a[m][3]=(__bf16)u0.w;
            a[m][4]=(__bf16)u1.x; a[m][5]=(__bf16)u1.y; a[m][6]=(__bf16)u1.z; a[m][7]=(__bf16)u1.w;
        }
        const __bf16* hb = hp + kt * 2048 + lane * 8;
#pragma unroll
        for (int nt = 0; nt < 4; ++nt) {
            bf16x8 bv = *reinterpret_cast<const bf16x8*>(hb + nt * 512);
            acc[nt][0] = __builtin_amdgcn_mfma_f32_16x16x32_bf16(a[0], bv, acc[nt][0], 0, 0, 0);
            acc[nt][1] = __builtin_amdgcn_mfma_f32_16x16x32_bf16(a[1], bv, acc[nt][1], 0, 0, 0);
        }
    }

#pragma unroll
    for (int m = 0; m < 2; ++m)
#pragma unroll
        for (int q = 0; q < 4; ++q) {
            int row = rb + m * 16 + kq * 4 + q;
#pragma unroll
            for (int z = 0; z < 2; ++z) {
                int zc = z * 16 + r16;
                float mu = acc[z][m][q] + mub[zc];
                float lv = acc[z + 2][m][q] + lvb[zc];
                int idx = row * 32 + zc;
                omu[idx] = mu;
                olv[idx] = lv;
                float s = fmaf(eps[idx], expf(0.5f * lv), mu);
                osm[idx] = s;
                if (osb) osb[idx] = (__bf16)s;
            }
        }
}

extern "C" void kernel_launch(void* const* d_in, const int* in_sizes, int n_in,
                              void* d_out, int out_size, void* d_ws, size_t ws_size,
                              hipStream_t stream)
{
    const float* x    = (const float*)d_in[0];
    const float* eps1 = (const float*)d_in[1];
    const float* eps2 = (const float*)d_in[2];
    const float* z2W1 = (const float*)d_in[3];
    const float* z2U1 = (const float*)d_in[4];
    const float* z2b1 = (const float*)d_in[5];
    const float* z2W2 = (const float*)d_in[6];
    const float* z2U2 = (const float*)d_in[7];
    const float* z2b2 = (const float*)d_in[8];
    const float* z1W1 = (const float*)d_in[9];
    const float* z1U1 = (const float*)d_in[10];
    const float* z1b1 = (const float*)d_in[11];
    const float* z1W2 = (const float*)d_in[12];
    const float* z1U2 = (const float*)d_in[13];
    const float* z1b2 = (const float*)d_in[14];
    const float* mu2W = (const float*)d_in[15];
    const float* mu2b = (const float*)d_in[16];
    const float* lv2W = (const float*)d_in[17];
    const float* lv2b = (const float*)d_in[18];
    const float* mu1W = (const float*)d_in[19];
    const float* mu1b = (const float*)d_in[20];
    const float* lv1W = (const float*)d_in[21];
    const float* lv1b = (const float*)d_in[22];

    char* ws = (char*)d_ws;
    __bf16* wp   = (__bf16*)ws;                        // 3.74 MB
    __bf16* z2sb = (__bf16*)(ws + 4194304);            // 1 MB
    __bf16* xb   = (__bf16*)(ws + 5242880);            // 80 MB
    __bf16* h1a  = (__bf16*)(ws + 89128960);           // 8 MB each
    __bf16* h2a  = (__bf16*)(ws + 97517568);
    __bf16* h1b  = (__bf16*)(ws + 105906176);
    __bf16* h2b  = (__bf16*)(ws + 114294784);
    float*  c1   = (float*)(ws + 122683392);           // 16 MB each
    float*  c2   = (float*)(ws + 139460608);           // end 156,237,824

    __bf16* h1[2] = {h1a, h1b};
    __bf16* h2[2] = {h2a, h2b};

    float* out = (float*)d_out;
    const int BZ = B_SZ * 32;
    float* z1mu = out;           float* z1lv = out + BZ;     float* z1sm = out + 2 * BZ;
    float* z2mu = out + 3 * BZ;  float* z2lv = out + 4 * BZ; float* z2sm = out + 5 * BZ;

    xconv<<<B_SZ * T_SZ * 16 / 256, 256, 0, stream>>>(x, xb);
    prep_w<<<7296, 256, 0, stream>>>(z2W1, z2U1, z2W2, z2U2, z1W1, z1U1, z1W2, z1U2,
                                     mu2W, lv2W, mu1W, lv1W, wp);

    // ---- z2 branch ----
    step_gemm<3, 11, 3, 0, 1><<<256, 512, 0, stream>>>(xb, 0, h1a, nullptr,
                                                       wp + OFF_L1Z2, z2b1, c1, h1[0]);
    step_gemm<8, 16, 0, 1, 1><<<256, 512, 0, stream>>>(xb, 0, h1[0], h2a,
                                                       wp + OFF_L2Z2, z2b2, c2, h2[0]);
    for (int t = 1; t < T_SZ; ++t) {
        int cur = t & 1, prv = cur ^ 1;
        step_gemm<11, 11, 3, 0, 0><<<256, 512, 0, stream>>>(xb, t, h1[prv], nullptr,
                                                            wp + OFF_L1Z2, z2b1, c1, h1[cur]);
        step_gemm<16, 16, 0, 1, 0><<<256, 512, 0, stream>>>(xb, t, h1[cur], h2[prv],
                                                            wp + OFF_L2Z2, z2b2, c2, h2[cur]);
    }
    head_mfma<<<256, 128, 0, stream>>>(c1, c2, wp + OFF_HZ2, mu2b, lv2b, eps2,
                                       z2mu, z2lv, z2sm, z2sb);
    bcast_z2<<<B_SZ * 4 / 256, 256, 0, stream>>>(z2sb, xb);

    // ---- z1 branch ----
    step_gemm<4, 12, 4, 0, 1><<<256, 512, 0, stream>>>(xb, 0, h1a, nullptr,
                                                       wp + OFF_L1Z1, z1b1, c1, h1[0]);
    step_gemm<8, 16, 0, 1, 1><<<256, 512, 0, stream>>>(xb, 0, h1[0], h2a,
                                                       wp + OFF_L2Z1, z1b2, c2, h2[0]);
    for (int t = 1; t < T_SZ; ++t) {
        int cur = t & 1, prv = cur ^ 1;
        step_gemm<12, 12, 4, 0, 0><<<256, 512, 0, stream>>>(xb, t, h1[prv], nullptr,
                                                            wp + OFF_L1Z1, z1b1, c1, h1[cur]);
        step_gemm<16, 16, 0, 1, 0><<<256, 512, 0, stream>>>(xb, t, h1[cur], h2[prv],
                                                            wp + OFF_L2Z1, z1b2, c2, h2[cur]);
    }
    head_mfma<<<256, 128, 0, stream>>>(c1, c2, wp + OFF_HZ1, mu1b, lv1b, eps1,
                                       z1mu, z1lv, z1sm, nullptr);
}

// Round 11
// 2068.049 us; speedup vs baseline: 3.6280x; 1.0368x over previous
//
#include <hip/hip_runtime.h>
#include <hip/hip_bf16.h>

#define B_SZ 16384
#define T_SZ 20

typedef __attribute__((ext_vector_type(8))) __bf16 bf16x8;
typedef __attribute__((ext_vector_type(4))) float f32x4;

__device__ __forceinline__ float sigm(float x){ return 1.f/(1.f+__expf(-x)); }
__device__ __forceinline__ float tanh_(float x){ return 1.f-2.f/(__expf(2.f*x)+1.f); }

// packed weight element offsets (bf16 elements)
#define OFF_L1Z2 0
#define OFF_L2Z2 360448
#define OFF_L1Z1 884736
#define OFF_L2Z1 1277952
#define OFF_HZ2  1802240
#define OFF_HZ1  1835008
#define WP_TOT   1867776

// ---------------- weight prep (4-wgn layout, round-7 proven) ----------------
__global__ void prep_w(const float* __restrict__ W0, const float* __restrict__ U0,
                       const float* __restrict__ W1, const float* __restrict__ U1,
                       const float* __restrict__ W2, const float* __restrict__ U2,
                       const float* __restrict__ W3, const float* __restrict__ U3,
                       const float* __restrict__ muW2, const float* __restrict__ lvW2,
                       const float* __restrict__ muW1, const float* __restrict__ lvW1,
                       __bf16* __restrict__ wp)
{
    int idx = blockIdx.x * 256 + threadIdx.x;
    if (idx >= WP_TOT) return;
    if (idx < OFF_HZ2) {
        const float *W, *U;
        int Fx, Kx, KT, local;
        if (idx < OFF_L2Z2)      { W = W0; U = U0; Fx = 80;  Kx = 96;  KT = 11; local = idx; }
        else if (idx < OFF_L1Z1) { W = W1; U = U1; Fx = 256; Kx = 256; KT = 16; local = idx - OFF_L2Z2; }
        else if (idx < OFF_L2Z1) { W = W2; U = U2; Fx = 112; Kx = 128; KT = 12; local = idx - OFF_L1Z1; }
        else                     { W = W3; U = U3; Fx = 256; Kx = 256; KT = 16; local = idx - OFF_L2Z1; }
        int jj = local & 7, lane = (local >> 3) & 63, nt16 = (local >> 9) & 15, rest = local >> 13;
        int kt = rest % KT, wgn = rest / KT;
        int gate = nt16 & 3, hh = nt16 >> 2;
        int n = gate * 256 + wgn * 64 + hh * 16 + (lane & 15);
        int k = kt * 32 + ((lane >> 4) << 3) + jj;
        float v = (k < Fx) ? W[k * 1024 + n] : (k < Kx ? 0.f : U[(k - Kx) * 1024 + n]);
        wp[idx] = (__bf16)v;
    } else {
        int base = (idx < OFF_HZ1) ? OFF_HZ2 : OFF_HZ1;
        const float* mw = (idx < OFF_HZ1) ? muW2 : muW1;
        const float* lw = (idx < OFF_HZ1) ? lvW2 : lvW1;
        int local = idx - base;
        int jj = local & 7, lane = (local >> 3) & 63, nt = (local >> 9) & 3, kt = local >> 11;
        int k = kt * 32 + ((lane >> 4) << 3) + jj;
        int c16 = lane & 15;
        float v = (nt < 2) ? mw[k * 32 + nt * 16 + c16] : lw[k * 32 + (nt - 2) * 16 + c16];
        wp[idx] = (__bf16)v;
    }
}

// ---------------- x fp32 -> xb bf16 [B][T][128] (cols >=80 zero) ----------------
__global__ void xconv(const float* __restrict__ x, __bf16* __restrict__ xb)
{
    int idx = blockIdx.x * 256 + threadIdx.x;
    int c8 = idx & 15, row = idx >> 4;
    bf16x8 r;
    if (c8 < 10) {
        const float4* p = reinterpret_cast<const float4*>(x + (size_t)row * 80 + c8 * 8);
        float4 u0 = p[0], u1 = p[1];
        r[0]=(__bf16)u0.x; r[1]=(__bf16)u0.y; r[2]=(__bf16)u0.z; r[3]=(__bf16)u0.w;
        r[4]=(__bf16)u1.x; r[5]=(__bf16)u1.y; r[6]=(__bf16)u1.z; r[7]=(__bf16)u1.w;
    } else {
#pragma unroll
        for (int i = 0; i < 8; ++i) r[i] = (__bf16)0.f;
    }
    *reinterpret_cast<bf16x8*>(xb + (size_t)row * 128 + c8 * 8) = r;
}

// ---------------- broadcast z2 sample into xb cols 80..111 for all t ----------------
__global__ void bcast_z2(const __bf16* __restrict__ z2sb, __bf16* __restrict__ xb)
{
    int idx = blockIdx.x * 256 + threadIdx.x;
    int g = idx & 3, b = idx >> 2;
    bf16x8 v = *reinterpret_cast<const bf16x8*>(z2sb + (size_t)b * 32 + g * 8);
#pragma unroll
    for (int t = 0; t < T_SZ; ++t)
        *reinterpret_cast<bf16x8*>(xb + ((size_t)b * T_SZ + t) * 128 + 80 + g * 8) = v;
}

// ---------------- async 16B global -> LDS ----------------
__device__ __forceinline__ void stage16(const __bf16* g, __bf16* l)
{
    __builtin_amdgcn_global_load_lds(
        (const __attribute__((address_space(1))) unsigned*)g,
        (__attribute__((address_space(3))) unsigned*)l, 16, 0, 0);
}

// ---------------- one LSTM-layer GEMM + cell epilogue (round-7 body, verbatim) ----------------
// wg tile 256 rows x 256 packed cols; bidh = wgn*64 + mid.  block 512 = 8 waves (wr,wc).
// A staged in LDS ring-3 ([256][32] lane-linear, per-lane global src); B global->VGPR ring-3,
// 2 phases ahead; counted vmcnt = 2*(STG k+1 pending) + 4*(LDB k+2 pending); 1 barrier/phase.
template <int KT, int KTP, int XKT, int TWOH, int FIRST>
__device__ __forceinline__ void gemm_step(const __bf16* __restrict__ xb, int t,
          const __bf16* __restrict__ hA, const __bf16* __restrict__ hB,
          const __bf16* __restrict__ wpm, const float* __restrict__ bias,
          float* __restrict__ cbuf, __bf16* __restrict__ hout,
          __bf16 (&As)[3][8192], int bidh)
{
    const int tid = threadIdx.x;
    const int w = tid >> 6, lane = tid & 63;
    const int r16 = lane & 15, kq = lane >> 4;
    const int wr = w >> 2, wc = w & 3;
    const int mid = bidh & 63, wgn = bidh >> 6;
    const int rb = mid * 256;
    const __bf16* wpB = wpm + (size_t)wgn * KTP * 8192;
    const __bf16* pBW = wpB + wc * 2048 + lane * 8;

    const int srow0 = rb + w * 32 + (lane >> 2);
    const int ksub  = (lane & 3) * 8;
    const __bf16* pA0 = hA + (size_t)srow0 * 256 + ksub;
    const __bf16* pA1 = hA + (size_t)(srow0 + 16) * 256 + ksub;
    const __bf16* px0 = (XKT > 0) ? xb + ((size_t)srow0 * T_SZ + t) * 128 + ksub : pA0;
    const __bf16* px1 = (XKT > 0) ? xb + ((size_t)(srow0 + 16) * T_SZ + t) * 128 + ksub : pA1;
    const __bf16* pH0 = TWOH ? hB + (size_t)srow0 * 256 + ksub : pA0;
    const __bf16* pH1 = TWOH ? hB + (size_t)(srow0 + 16) * 256 + ksub : pA1;

    f32x4 acc[4][8];
#pragma unroll
    for (int g = 0; g < 4; ++g)
#pragma unroll
        for (int m = 0; m < 8; ++m) acc[g][m] = f32x4{0.f, 0.f, 0.f, 0.f};

    bf16x8 bR[3][4];

#define ASRC(K, P0, PA, PH_) \
    ((K) < XKT ? (P0) + (K) * 32 \
               : ((!TWOH || ((K) - XKT) < 8) ? (PA) + ((K) - XKT) * 32 \
                                             : (PH_) + ((K) - XKT - 8) * 32))
#define STG_A(K) { stage16(ASRC(K, px0, pA0, pH0), &As[(K) % 3][w * 1024]); \
                   stage16(ASRC(K, px1, pA1, pH1), &As[(K) % 3][w * 1024 + 512]); }
#define LDB(K) { _Pragma("unroll") for (int nt = 0; nt < 4; ++nt) \
                   bR[(K) % 3][nt] = *reinterpret_cast<const bf16x8*>(pBW + (size_t)(K) * 8192 + nt * 512); }
#define CMP(K) { const __bf16* ab_ = &As[(K) % 3][(wr * 128 + r16) * 32 + kq * 8]; \
    bf16x8 a_[8]; \
    _Pragma("unroll") for (int m = 0; m < 8; ++m) \
        a_[m] = *reinterpret_cast<const bf16x8*>(ab_ + m * 512); \
    _Pragma("unroll") for (int m = 0; m < 8; ++m) \
        _Pragma("unroll") for (int g = 0; g < 4; ++g) \
            acc[g][m] = __builtin_amdgcn_mfma_f32_16x16x32_bf16(a_[m], bR[(K) % 3][g], acc[g][m], 0, 0, 0); }
#define PH(K) if constexpr ((K) < KT) { \
    __builtin_amdgcn_sched_barrier(0); \
    if constexpr ((K) + 1 < KT) STG_A((K) + 1); \
    if constexpr ((K) + 2 < KT) LDB((K) + 2); \
    { constexpr int c_ = 2 * (((K) + 1 < KT) ? 1 : 0) + 4 * (((K) + 2 < KT) ? 1 : 0); \
      asm volatile("s_waitcnt vmcnt(%0)" :: "n"(c_) : "memory"); } \
    __builtin_amdgcn_s_barrier(); \
    __builtin_amdgcn_sched_barrier(0); \
    CMP(K); }

    // prologue
    STG_A(0); LDB(0);
    if constexpr (KT > 1) LDB(1);

    PH(0)  PH(1)  PH(2)  PH(3)  PH(4)  PH(5)  PH(6)  PH(7)
    PH(8)  PH(9)  PH(10) PH(11) PH(12) PH(13) PH(14) PH(15)

#undef ASRC
#undef STG_A
#undef LDB
#undef CMP
#undef PH

    // ---- fused LSTM cell epilogue (wave owns 16 h-cols, all 4 gates lane-local) ----
    const int hcol = wgn * 64 + wc * 16 + r16;
    float bg[4];
#pragma unroll
    for (int g = 0; g < 4; ++g) bg[g] = bias[g * 256 + hcol];

#pragma unroll
    for (int m = 0; m < 8; ++m) {
        f32x4 zi = acc[0][m], zf = acc[1][m], zg = acc[2][m], zo = acc[3][m];
#pragma unroll
        for (int q = 0; q < 4; ++q) {
            int row = rb + wr * 128 + m * 16 + kq * 4 + q;
            size_t off = (size_t)row * 256 + hcol;
            float cn;
            if (FIRST) {
                cn = sigm(zi[q] + bg[0]) * tanh_(zg[q] + bg[2]);
            } else {
                float co = cbuf[off];
                cn = sigm(zf[q] + bg[1]) * co + sigm(zi[q] + bg[0]) * tanh_(zg[q] + bg[2]);
            }
            cbuf[off] = cn;
            hout[off] = (__bf16)(sigm(zo[q] + bg[3]) * tanh_(cn));
        }
    }
}

// ---------------- fused step: L2(t) and L1(t+1) are independent given h1(t) ----------------
// PHASE 0: prologue, grid 256 — L1(0) only (KT=XKT, FIRST).
// PHASE 1: steady,   grid 512 — blocks [0,256) do L2(t) (KT=8 if FIRST2 else 16);
//                               blocks [256,512) do L1(t+1) (KT=KT1).
// PHASE 2: epilogue, grid 256 — L2(19) only.
template <int XKT, int KT1, int PHASE, int FIRST2>
__global__ void __launch_bounds__(512, 2)
fused_step(const __bf16* __restrict__ xb, int t,
           const __bf16* __restrict__ h1cur, __bf16* __restrict__ h1nxt,
           const __bf16* __restrict__ h2prv, __bf16* __restrict__ h2cur,
           const __bf16* __restrict__ wp1, const __bf16* __restrict__ wp2,
           const float* __restrict__ b1, const float* __restrict__ b2,
           float* __restrict__ c1, float* __restrict__ c2)
{
    __shared__ __align__(16) __bf16 As[3][8192];
    const int bidh = blockIdx.x & 255;

    if constexpr (PHASE == 0) {
        gemm_step<XKT, KT1, XKT, 0, 1>(xb, t + 1, h1cur, nullptr, wp1, b1, c1, h1nxt, As, bidh);
    } else if constexpr (PHASE == 2) {
        gemm_step<16, 16, 0, 1, 0>(xb, t, h1cur, h2prv, wp2, b2, c2, h2cur, As, bidh);
    } else {
        if ((blockIdx.x >> 8) == 0) {
            constexpr int KT2 = FIRST2 ? 8 : 16;
            gemm_step<KT2, 16, 0, 1, FIRST2>(xb, t, h1cur, h2prv, wp2, b2, c2, h2cur, As, bidh);
        } else {
            gemm_step<KT1, KT1, XKT, 0, 0>(xb, t + 1, h1cur, nullptr, wp1, b1, c1, h1nxt, As, bidh);
        }
    }
}

// ---------------- MFMA head (unchanged; reads row-major c) ----------------
__global__ void __launch_bounds__(128, 4)
head_mfma(const float* __restrict__ c1, const float* __restrict__ c2,
          const __bf16* __restrict__ hp, const float* __restrict__ mub,
          const float* __restrict__ lvb, const float* __restrict__ eps,
          float* __restrict__ omu, float* __restrict__ olv, float* __restrict__ osm,
          __bf16* __restrict__ osb)
{
    const int tid = threadIdx.x;
    const int w = tid >> 6, lane = tid & 63;
    const int r16 = lane & 15, kq = lane >> 4;
    const int rb = blockIdx.x * 64 + w * 32;

    f32x4 acc[4][2];
#pragma unroll
    for (int nt = 0; nt < 4; ++nt)
#pragma unroll
        for (int m = 0; m < 2; ++m) acc[nt][m] = f32x4{0.f, 0.f, 0.f, 0.f};

#pragma unroll
    for (int kt = 0; kt < 16; ++kt) {
        const float* cs = (kt < 8) ? c1 : c2;
        int k = (kt & 7) * 32 + kq * 8;
        bf16x8 a[2];
#pragma unroll
        for (int m = 0; m < 2; ++m) {
            const float* pr = cs + (size_t)(rb + m * 16 + r16) * 256 + k;
            float4 u0 = reinterpret_cast<const float4*>(pr)[0];
            float4 u1 = reinterpret_cast<const float4*>(pr)[1];
            a[m][0]=(__bf16)u0.x; a[m][1]=(__bf16)u0.y; a[m][2]=(__bf16)u0.z; a[m][3]=(__bf16)u0.w;
            a[m][4]=(__bf16)u1.x; a[m][5]=(__bf16)u1.y; a[m][6]=(__bf16)u1.z; a[m][7]=(__bf16)u1.w;
        }
        const __bf16* hb = hp + kt * 2048 + lane * 8;
#pragma unroll
        for (int nt = 0; nt < 4; ++nt) {
            bf16x8 bv = *reinterpret_cast<const bf16x8*>(hb + nt * 512);
            acc[nt][0] = __builtin_amdgcn_mfma_f32_16x16x32_bf16(a[0], bv, acc[nt][0], 0, 0, 0);
            acc[nt][1] = __builtin_amdgcn_mfma_f32_16x16x32_bf16(a[1], bv, acc[nt][1], 0, 0, 0);
        }
    }

#pragma unroll
    for (int m = 0; m < 2; ++m)
#pragma unroll
        for (int q = 0; q < 4; ++q) {
            int row = rb + m * 16 + kq * 4 + q;
#pragma unroll
            for (int z = 0; z < 2; ++z) {
                int zc = z * 16 + r16;
                float mu = acc[z][m][q] + mub[zc];
                float lv = acc[z + 2][m][q] + lvb[zc];
                int idx = row * 32 + zc;
                omu[idx] = mu;
                olv[idx] = lv;
                float s = fmaf(eps[idx], expf(0.5f * lv), mu);
                osm[idx] = s;
                if (osb) osb[idx] = (__bf16)s;
            }
        }
}

extern "C" void kernel_launch(void* const* d_in, const int* in_sizes, int n_in,
                              void* d_out, int out_size, void* d_ws, size_t ws_size,
                              hipStream_t stream)
{
    const float* x    = (const float*)d_in[0];
    const float* eps1 = (const float*)d_in[1];
    const float* eps2 = (const float*)d_in[2];
    const float* z2W1 = (const float*)d_in[3];
    const float* z2U1 = (const float*)d_in[4];
    const float* z2b1 = (const float*)d_in[5];
    const float* z2W2 = (const float*)d_in[6];
    const float* z2U2 = (const float*)d_in[7];
    const float* z2b2 = (const float*)d_in[8];
    const float* z1W1 = (const float*)d_in[9];
    const float* z1U1 = (const float*)d_in[10];
    const float* z1b1 = (const float*)d_in[11];
    const float* z1W2 = (const float*)d_in[12];
    const float* z1U2 = (const float*)d_in[13];
    const float* z1b2 = (const float*)d_in[14];
    const float* mu2W = (const float*)d_in[15];
    const float* mu2b = (const float*)d_in[16];
    const float* lv2W = (const float*)d_in[17];
    const float* lv2b = (const float*)d_in[18];
    const float* mu1W = (const float*)d_in[19];
    const float* mu1b = (const float*)d_in[20];
    const float* lv1W = (const float*)d_in[21];
    const float* lv1b = (const float*)d_in[22];

    char* ws = (char*)d_ws;
    __bf16* wp   = (__bf16*)ws;                        // 3.74 MB
    __bf16* z2sb = (__bf16*)(ws + 4194304);            // 1 MB
    __bf16* xb   = (__bf16*)(ws + 5242880);            // 80 MB
    __bf16* h1a  = (__bf16*)(ws + 89128960);           // 8 MB each
    __bf16* h1b  = (__bf16*)(ws + 97517568);
    __bf16* h2a  = (__bf16*)(ws + 105906176);
    __bf16* h2b  = (__bf16*)(ws + 114294784);
    float*  c1   = (float*)(ws + 122683392);           // 16 MB each
    float*  c2   = (float*)(ws + 139460608);           // end 156,237,824

    __bf16* h1[2] = {h1a, h1b};
    __bf16* h2[2] = {h2a, h2b};

    float* out = (float*)d_out;
    const int BZ = B_SZ * 32;
    float* z1mu = out;           float* z1lv = out + BZ;     float* z1sm = out + 2 * BZ;
    float* z2mu = out + 3 * BZ;  float* z2lv = out + 4 * BZ; float* z2sm = out + 5 * BZ;

    xconv<<<B_SZ * T_SZ * 16 / 256, 256, 0, stream>>>(x, xb);
    prep_w<<<7296, 256, 0, stream>>>(z2W1, z2U1, z2W2, z2U2, z1W1, z1U1, z1W2, z1U2,
                                     mu2W, lv2W, mu1W, lv1W, wp);

    // ---- z2 branch (XKT=3, KT1=11) ----
    {
        const __bf16* wpa = wp + OFF_L1Z2;
        const __bf16* wpb = wp + OFF_L2Z2;
        // prologue: L1(0)
        fused_step<3, 11, 0, 0><<<256, 512, 0, stream>>>(xb, -1, h1[0], h1[0], h2[0], h2[0],
                                                         wpa, wpb, z2b1, z2b2, c1, c2);
        // t = 0: L2(0) [FIRST] + L1(1)
        fused_step<3, 11, 1, 1><<<512, 512, 0, stream>>>(xb, 0, h1[0], h1[1], h2[1], h2[0],
                                                         wpa, wpb, z2b1, z2b2, c1, c2);
        for (int t = 1; t < T_SZ - 1; ++t)
            fused_step<3, 11, 1, 0><<<512, 512, 0, stream>>>(xb, t, h1[t & 1], h1[(t + 1) & 1],
                                                             h2[(t + 1) & 1], h2[t & 1],
                                                             wpa, wpb, z2b1, z2b2, c1, c2);
        // epilogue: L2(19)
        fused_step<3, 11, 2, 0><<<256, 512, 0, stream>>>(xb, 19, h1[1], h1[0], h2[0], h2[1],
                                                         wpa, wpb, z2b1, z2b2, c1, c2);
    }
    head_mfma<<<256, 128, 0, stream>>>(c1, c2, wp + OFF_HZ2, mu2b, lv2b, eps2,
                                       z2mu, z2lv, z2sm, z2sb);
    bcast_z2<<<B_SZ * 4 / 256, 256, 0, stream>>>(z2sb, xb);

    // ---- z1 branch (XKT=4, KT1=12) ----
    {
        const __bf16* wpa = wp + OFF_L1Z1;
        const __bf16* wpb = wp + OFF_L2Z1;
        fused_step<4, 12, 0, 0><<<256, 512, 0, stream>>>(xb, -1, h1[0], h1[0], h2[0], h2[0],
                                                         wpa, wpb, z1b1, z1b2, c1, c2);
        fused_step<4, 12, 1, 1><<<512, 512, 0, stream>>>(xb, 0, h1[0], h1[1], h2[1], h2[0],
                                                         wpa, wpb, z1b1, z1b2, c1, c2);
        for (int t = 1; t < T_SZ - 1; ++t)
            fused_step<4, 12, 1, 0><<<512, 512, 0, stream>>>(xb, t, h1[t & 1], h1[(t + 1) & 1],
                                                             h2[(t + 1) & 1], h2[t & 1],
                                                             wpa, wpb, z1b1, z1b2, c1, c2);
        fused_step<4, 12, 2, 0><<<256, 512, 0, stream>>>(xb, 19, h1[1], h1[0], h2[0], h2[1],
                                                         wpa, wpb, z1b1, z1b2, c1, c2);
    }
    head_mfma<<<256, 128, 0, stream>>>(c1, c2, wp + OFF_HZ1, mu1b, lv1b, eps1,
                                       z1mu, z1lv, z1sm, nullptr);
}